// Round 9
// baseline (127.836 us; speedup 1.0000x reference)
//
#include <hip/hip_runtime.h>

typedef unsigned short u16;
typedef float f32x4 __attribute__((ext_vector_type(4)));
typedef float f32x16 __attribute__((ext_vector_type(16)));
typedef __bf16 bf16x8 __attribute__((ext_vector_type(8)));

#define MFMA16(a, b, c) __builtin_amdgcn_mfma_f32_16x16x32_bf16((a), (b), (c), 0, 0, 0)
#define MFMA32(a, b, c) __builtin_amdgcn_mfma_f32_32x32x16_bf16((a), (b), (c), 0, 0, 0)

#define B_ 8
#define H_ 8
#define S_ 1024

__device__ __forceinline__ u16 f2bf(float f) {
  unsigned u = __float_as_uint(f);
  return (u16)((u + 0x7fffu + ((u >> 16) & 1u)) >> 16);
}
// pack 2 f32 -> 2 bf16 in one instr (dst.lo = a, dst.hi = b)
__device__ __forceinline__ unsigned cvtpk(float a, float b) {
  unsigned r;
  asm("v_cvt_pk_bf16_f32 %0, %1, %2" : "=v"(r) : "v"(a), "v"(b));
  return r;
}
// after: a = [a_lo | b_lo], b = [a_hi | b_hi]  (32-lane half swap)
__device__ __forceinline__ void plswap(unsigned& a, unsigned& b) {
  asm("v_permlane32_swap_b32 %0, %1" : "+v"(a), "+v"(b));
}
// async global->LDS, 16B per lane. LDS dest = wave-uniform base + lane*16.
__device__ __forceinline__ void gload16(const void* g, void* l) {
  __builtin_amdgcn_global_load_lds((__attribute__((address_space(1))) const void*)g,
                                   (__attribute__((address_space(3))) void*)l, 16, 0, 0);
}

// ---------------- all fp32->bf16 converts in one dispatch ----------------
__global__ void __launch_bounds__(256) convAll(const float* __restrict__ q, const float* __restrict__ k,
                                               const float* __restrict__ v, const float* __restrict__ Wq,
                                               const float* __restrict__ Wk, const float* __restrict__ Wv,
                                               const float* __restrict__ Wo, const float* __restrict__ relk,
                                               u16* __restrict__ dq, u16* __restrict__ dk, u16* __restrict__ dv,
                                               u16* __restrict__ dWq, u16* __restrict__ dWk, u16* __restrict__ dWv,
                                               u16* __restrict__ dWo, u16* __restrict__ drelk) {
  const int bid = blockIdx.x;
  const float* s; u16* d; size_t off;
  if (bid < 12288) {
    size_t i4 = (size_t)bid * 256 + threadIdx.x;   // 3*1048576 float4s
    int tsel = (int)(i4 >> 20);
    off = (i4 & 1048575) << 2;
    s = tsel == 0 ? q : (tsel == 1 ? k : v);
    d = tsel == 0 ? dq : (tsel == 1 ? dk : dv);
  } else {
    size_t i = ((size_t)(bid - 12288) * 256 + threadIdx.x) << 2;
    if (i >= 1050688) return; // 4*262144 + 33*64
    if (i < 262144)       { s = Wq; d = dWq; off = i; }
    else if (i < 524288)  { s = Wk; d = dWk; off = i - 262144; }
    else if (i < 786432)  { s = Wv; d = dWv; off = i - 524288; }
    else if (i < 1048576) { s = Wo; d = dWo; off = i - 786432; }
    else                  { s = relk; d = drelk; off = i - 1048576; }
  }
  float4 f = *(const float4*)(s + off);
  uint2 o;
  o.x = cvtpk(f.x, f.y);
  o.y = cvtpk(f.z, f.w);
  *(uint2*)(d + off) = o;
}

// ---------------- fused Q/K/V projection GEMM (768 blocks) ----------------
// seg 0: Q -> bf16 head-split [B,H,S,64]; seg 1: K same; seg 2: V -> transposed [B*H,64,S].
__global__ void __launch_bounds__(256) qkv_gemm(const u16* __restrict__ Xq, const u16* __restrict__ Xk,
                                                const u16* __restrict__ Xv, const u16* __restrict__ Wqb,
                                                const u16* __restrict__ Wkb, const u16* __restrict__ Wvb,
                                                const float* __restrict__ bq, const float* __restrict__ bk,
                                                const float* __restrict__ bv, u16* __restrict__ Qh,
                                                u16* __restrict__ Kh, u16* __restrict__ Vt) {
  __shared__ u16 As[128 * 64];
  __shared__ u16 Bs[128 * 64];
  const int seg = blockIdx.x >> 8, bid = blockIdx.x & 255;
  const u16* A = seg == 0 ? Xq : (seg == 1 ? Xk : Xv);
  const u16* W = seg == 0 ? Wqb : (seg == 1 ? Wkb : Wvb);
  const float* bias = seg == 0 ? bq : (seg == 1 ? bk : bv);
  const int tid = threadIdx.x, lane = tid & 63, wid = tid >> 6;
  const int c = lane & 15, g = lane >> 4;
  const int bm = bid >> 2, bn = bid & 3;
  const int m0 = bm << 7, n0 = bn << 7;
  const int wrow = (wid >> 1) << 6, wcol = (wid & 1) << 6;

  const f32x4 ZF = {0.f, 0.f, 0.f, 0.f};
  f32x4 acc[4][4];
#pragma unroll
  for (int i = 0; i < 4; ++i)
#pragma unroll
    for (int j = 0; j < 4; ++j) acc[i][j] = ZF;

  for (int kt = 0; kt < 512; kt += 64) {
    __syncthreads();
#pragma unroll
    for (int i = 0; i < 4; ++i) {
      int Lb = ((wid << 2) | i) << 10;
      int L = Lb + lane * 16;
      int row = L >> 7;                                 // 0..127
      int off = (L & 127) ^ ((row & 7) << 4);           // pre-swizzled source
      gload16((const char*)A + ((((size_t)(m0 + row)) << 9) + kt) * 2 + off, (char*)As + Lb);
      gload16((const char*)W + ((((size_t)(n0 + row)) << 9) + kt) * 2 + off, (char*)Bs + Lb);
    }
    __syncthreads();
#pragma unroll
    for (int kk = 0; kk < 2; ++kk) {
      bf16x8 af[4], bfr[4];
#pragma unroll
      for (int rt = 0; rt < 4; ++rt) {
        int row = wrow + (rt << 4) + c;
        af[rt] = *(const bf16x8*)((const char*)As + row * 128 + (((kk << 6) | (g << 4)) ^ ((row & 7) << 4)));
      }
#pragma unroll
      for (int ct = 0; ct < 4; ++ct) {
        int row = wcol + (ct << 4) + c;
        bfr[ct] = *(const bf16x8*)((const char*)Bs + row * 128 + (((kk << 6) | (g << 4)) ^ ((row & 7) << 4)));
      }
#pragma unroll
      for (int rt = 0; rt < 4; ++rt)
#pragma unroll
        for (int ct = 0; ct < 4; ++ct) acc[rt][ct] = MFMA16(af[rt], bfr[ct], acc[rt][ct]);
    }
  }

#pragma unroll
  for (int rt = 0; rt < 4; ++rt)
#pragma unroll
    for (int ct = 0; ct < 4; ++ct) {
      int n = n0 + wcol + (ct << 4) + c;
      float bv2 = bias[n];
      if (seg == 2) {
        int b2 = m0 >> 10;
        int sbase = (m0 & 1023) + wrow + (rt << 4) + (g << 2);
        int h2 = n >> 6, d2 = n & 63;
        uint2 o;
        o.x = cvtpk(acc[rt][ct][0] + bv2, acc[rt][ct][1] + bv2);
        o.y = cvtpk(acc[rt][ct][2] + bv2, acc[rt][ct][3] + bv2);
        *(uint2*)(Vt + ((((size_t)((b2 << 3) + h2) << 6) + d2) << 10) + sbase) = o;
      } else {
        u16* out = seg == 0 ? Qh : Kh;
#pragma unroll
        for (int r = 0; r < 4; ++r) {
          int m = m0 + wrow + (rt << 4) + (g << 2) + r;
          int b = m >> 10, s = m & 1023, h = n >> 6, d = n & 63;
          out[(((((size_t)(b * H_ + h)) << 10) + s) << 6) + d] = f2bf(acc[rt][ct][r] + bv2);
        }
      }
    }
}

// ---------------- output GEMM: C fp32 [M][512] = A(bf16) @ W(bf16)^T + bias ----------------
__global__ void __launch_bounds__(256) gemm_out(const u16* __restrict__ A, const u16* __restrict__ W,
                                                const float* __restrict__ bias, float* __restrict__ out) {
  __shared__ u16 As[128 * 64];
  __shared__ u16 Bs[128 * 64];
  const int tid = threadIdx.x, lane = tid & 63, wid = tid >> 6;
  const int c = lane & 15, g = lane >> 4;
  const int bm = blockIdx.x >> 2, bn = blockIdx.x & 3;
  const int m0 = bm << 7, n0 = bn << 7;
  const int wrow = (wid >> 1) << 6, wcol = (wid & 1) << 6;

  const f32x4 ZF = {0.f, 0.f, 0.f, 0.f};
  f32x4 acc[4][4];
#pragma unroll
  for (int i = 0; i < 4; ++i)
#pragma unroll
    for (int j = 0; j < 4; ++j) acc[i][j] = ZF;

  for (int kt = 0; kt < 512; kt += 64) {
    __syncthreads();
#pragma unroll
    for (int i = 0; i < 4; ++i) {
      int Lb = ((wid << 2) | i) << 10;
      int L = Lb + lane * 16;
      int row = L >> 7;
      int off = (L & 127) ^ ((row & 7) << 4);
      gload16((const char*)A + ((((size_t)(m0 + row)) << 9) + kt) * 2 + off, (char*)As + Lb);
      gload16((const char*)W + ((((size_t)(n0 + row)) << 9) + kt) * 2 + off, (char*)Bs + Lb);
    }
    __syncthreads();
#pragma unroll
    for (int kk = 0; kk < 2; ++kk) {
      bf16x8 af[4], bfr[4];
#pragma unroll
      for (int rt = 0; rt < 4; ++rt) {
        int row = wrow + (rt << 4) + c;
        af[rt] = *(const bf16x8*)((const char*)As + row * 128 + (((kk << 6) | (g << 4)) ^ ((row & 7) << 4)));
      }
#pragma unroll
      for (int ct = 0; ct < 4; ++ct) {
        int row = wcol + (ct << 4) + c;
        bfr[ct] = *(const bf16x8*)((const char*)Bs + row * 128 + (((kk << 6) | (g << 4)) ^ ((row & 7) << 4)));
      }
#pragma unroll
      for (int rt = 0; rt < 4; ++rt)
#pragma unroll
        for (int ct = 0; ct < 4; ++ct) acc[rt][ct] = MFMA16(af[rt], bfr[ct], acc[rt][ct]);
    }
  }

#pragma unroll
  for (int rt = 0; rt < 4; ++rt)
#pragma unroll
    for (int ct = 0; ct < 4; ++ct) {
      int n = n0 + wcol + (ct << 4) + c;
      float bv = bias[n];
#pragma unroll
      for (int r = 0; r < 4; ++r) {
        int m = m0 + wrow + (rt << 4) + (g << 2) + r;
        out[(((size_t)m) << 9) + n] = acc[rt][ct][r] + bv;
      }
    }
}

// ---------------- flash attention: 32x32 MFMA, barrier-free, direct-from-global K/V ----------------
// 512 blocks x 4 waves x 32 q. K (8KB/tile, contiguous) and V^T (128B slices) are L1/L2-resident;
// MFMA fragments are loaded straight from global (16B/lane), no LDS staging, no main-loop barriers.
__global__ void __launch_bounds__(256) flash_kernel(const u16* __restrict__ Qh, const u16* __restrict__ Kh,
                                                    const u16* __restrict__ Vt, const u16* __restrict__ relkb,
                                                    const float* __restrict__ relv, u16* __restrict__ Xout) {
  __shared__ float qrelT[33 * 128];   // [r][q] exp2-domain bias; overlaid by rvT (bf16) in epilogue
  __shared__ u16 Pband[128 * 32];     // unnormalized band probs; slot 0 = low bucket
  __shared__ float rv32S[64];
  __shared__ float2 normS[128];       // {inv, hsum} per q

  const int tid = threadIdx.x, lane = tid & 63, wid = tid >> 6;   // wid 0..3
  const int c32 = lane & 31, hi = lane >> 5;
  // XCD swizzle: 512 blocks; XCD x gets bh in [x*8, x*8+8)
  const int swz = ((blockIdx.x & 7) << 6) | (blockIdx.x >> 3);
  const int bh = swz >> 3, qt = swz & 7;
  const int qbase = qt << 7;
  const size_t rowbase = ((size_t)bh) << 10;
  const int wavebase = wid << 5;
  const int qloc = wavebase + c32;
  const float K1 = 0.51013619f;   // (1/sqrt(8)) * log2(e)
  const float C0 = 24.0f;

  // zero Pband (8 KB) + rv32
  ((uint4*)Pband)[tid] = uint4{0, 0, 0, 0};
  ((uint4*)Pband)[tid + 256] = uint4{0, 0, 0, 0};
  if (tid < 64) rv32S[tid] = relv[2048 + tid];

  // ---- prologue: qrelT via 16x16 MFMAs (2 q-halves per wave) ----
  {
    const int c = lane & 15, g = lane >> 4;
    const f32x4 ZF4 = {0.f, 0.f, 0.f, 0.f};
#pragma unroll
    for (int hf = 0; hf < 2; ++hf) {
      const int q16 = wavebase + (hf << 4) + c;
      const u16* qp = Qh + ((rowbase + qbase + q16) << 6);
      bf16x8 qa0 = *(const bf16x8*)(qp + (g << 3));
      bf16x8 qa1 = *(const bf16x8*)(qp + 32 + (g << 3));
#pragma unroll
      for (int t = 0; t < 3; ++t) {
        int rr = t * 16 + c; if (rr > 32) rr = 32;
        f32x4 qr = ZF4;
        qr = MFMA16(*(const bf16x8*)(relkb + (rr << 6) + (g << 3)), qa0, qr);
        qr = MFMA16(*(const bf16x8*)(relkb + (rr << 6) + 32 + (g << 3)), qa1, qr);
#pragma unroll
        for (int j = 0; j < 4; ++j) {
          int r = t * 16 + (g << 2) + j;
          if (r < 33) qrelT[(r << 7) + q16] = qr[j] * K1 - C0;
        }
      }
    }
  }

  // main-loop Q B-fragments (col = own q, k-slice per ks/hi)
  bf16x8 qb[4];
  {
    const u16* qp = Qh + ((rowbase + qbase + qloc) << 6);
#pragma unroll
    for (int ks = 0; ks < 4; ++ks) qb[ks] = *(const bf16x8*)(qp + (ks << 4) + (hi << 3));
  }

  __syncthreads();   // Pband, rv32S, qrelT visible to all waves (only barrier before epilogue)

  const float bias_lo = qrelT[qloc];
  const float bias_hi = qrelT[(32 << 7) + qloc];

  // wave-invariant global fragment base pointers
  const u16* Kbh = Kh + (rowbase << 6);            // [1024 s][64 d]
  const u16* Vbh = Vt + ((size_t)bh << 16);        // [64 d][1024 s]
  const u16* kp0 = Kbh + (c32 << 6) + (hi << 3);   // + k64*64 + mt*2048 + ks*16
  const u16* vp0 = Vbh + ((size_t)c32 << 10) + (hi << 3);  // + nt*32768 + k64 + ks*16

  const f32x16 Z16 = {0.f,0.f,0.f,0.f,0.f,0.f,0.f,0.f,0.f,0.f,0.f,0.f,0.f,0.f,0.f,0.f};
  f32x16 acc0 = Z16, acc1 = Z16;
  float lsum = 0.f, lowsum = 0.f, psum = 0.f;

  for (int kt = 0; kt < 16; ++kt) {
    const int k64 = kt << 6;
    // issue all 16 fragment loads for this tile (L1/L2-served; no staging)
    const u16* kp = kp0 + (k64 << 6);
    const u16* vp = vp0 + k64;
    bf16x8 ka0[4], ka1[4], vb0[4], vb1[4];
#pragma unroll
    for (int ks = 0; ks < 4; ++ks) {
      ka0[ks] = *(const bf16x8*)(kp + (ks << 4));
      ka1[ks] = *(const bf16x8*)(kp + 2048 + (ks << 4));
      vb0[ks] = *(const bf16x8*)(vp + (ks << 4));
      vb1[ks] = *(const bf16x8*)(vp + 32768 + (ks << 4));
    }

    // QK^T swapped (A=K, B=Q): sA/sB = S[k-rows][q=own]
    f32x16 sA = Z16, sB = Z16;
    __builtin_amdgcn_s_setprio(1);
#pragma unroll
    for (int ks = 0; ks < 4; ++ks) {
      sA = MFMA32(ka0[ks], qb[ks], sA);
      sB = MFMA32(ka1[ks], qb[ks], sB);
    }
    __builtin_amdgcn_s_setprio(0);

    // wave-uniform bucket classification: E = k-tile start - wave q start
    const int E = k64 - qbase - wavebase;
    if (E >= 48) {              // all dlt >= 17: high bucket
      float ps[4] = {0.f, 0.f, 0.f, 0.f};
#pragma unroll
      for (int r = 0; r < 16; ++r) {
        float pe = __builtin_amdgcn_exp2f(fmaf(sA[r], K1, bias_hi)); sA[r] = pe;
        float pf = __builtin_amdgcn_exp2f(fmaf(sB[r], K1, bias_hi)); sB[r] = pf;
        ps[r & 3] += pe + pf;
      }
      lsum += (ps[0] + ps[1]) + (ps[2] + ps[3]);
    } else if (E <= -80) {      // all dlt <= -17: low bucket
      float ps[4] = {0.f, 0.f, 0.f, 0.f};
#pragma unroll
      for (int r = 0; r < 16; ++r) {
        float pe = __builtin_amdgcn_exp2f(fmaf(sA[r], K1, bias_lo)); sA[r] = pe;
        float pf = __builtin_amdgcn_exp2f(fmaf(sB[r], K1, bias_lo)); sB[r] = pf;
        ps[r & 3] += pe + pf;
      }
      float t0 = (ps[0] + ps[1]) + (ps[2] + ps[3]);
      lsum += t0; lowsum += t0;
    } else {                    // boundary tiles (2 of 16 per wave)
      const int base = E - c32 + (hi << 2);
#pragma unroll
      for (int mt = 0; mt < 2; ++mt) {
        f32x16& s = mt ? sB : sA;
#pragma unroll
        for (int r = 0; r < 16; ++r) {
          int dlt = base + (mt << 5) + (r & 3) + ((r >> 2) << 3);
          int idx = dlt < -16 ? 0 : (dlt > 16 ? 32 : dlt + 16);
          float pe = __builtin_amdgcn_exp2f(fmaf(s[r], K1, qrelT[(idx << 7) + qloc]));
          s[r] = pe;
          lsum += pe;
          if (dlt <= -16) lowsum += pe;
          else if (dlt < 16) { psum += pe; Pband[(qloc << 5) + dlt + 16] = f2bf(pe); }
        }
      }
    }

    // P -> PV A-fragments, in-register: 16 cvt_pk + 8 permlane32_swap
    unsigned uA[8], uB[8];
#pragma unroll
    for (int j = 0; j < 8; ++j) {
      uA[j] = cvtpk(sA[2 * j], sA[2 * j + 1]);
      uB[j] = cvtpk(sB[2 * j], sB[2 * j + 1]);
    }
    bf16x8 pa[4];
#pragma unroll
    for (int ks = 0; ks < 4; ++ks) {
      int jb = (ks & 1) << 2;
      unsigned w0, w1, w2, w3;
      if (ks < 2) { w0 = uA[jb]; w2 = uA[jb + 2]; w1 = uA[jb + 1]; w3 = uA[jb + 3]; }
      else        { w0 = uB[jb]; w2 = uB[jb + 2]; w1 = uB[jb + 1]; w3 = uB[jb + 3]; }
      plswap(w0, w2);
      plswap(w1, w3);
      uint4 t4{w0, w1, w2, w3};
      pa[ks] = __builtin_bit_cast(bf16x8, t4);
    }

    // PV (A=P, B=V): acc0 cols d = c32, acc1 cols d = 32+c32, rows q = crow(r,hi)
    __builtin_amdgcn_s_setprio(1);
#pragma unroll
    for (int ks = 0; ks < 4; ++ks) {
      acc0 = MFMA32(pa[ks], vb0[ks], acc0);
      acc1 = MFMA32(pa[ks], vb1[ks], acc1);
    }
    __builtin_amdgcn_s_setprio(0);
  }

  // ---- epilogue ----
  lsum += __shfl_xor(lsum, 32);
  lowsum += __shfl_xor(lowsum, 32);
  psum += __shfl_xor(psum, 32);
  const float inv = 1.f / lsum;
  const float hsum = lsum - lowsum - psum;   // unnormalized high-bucket mass
  if (lane < 32) {
    Pband[qloc << 5] = f2bf(lowsum);
    normS[qloc] = float2{inv, hsum};
  }
  __syncthreads();
  // overlay rv^T (bf16 [64 d][32 r]) into dead qrelT
  u16* rvT = (u16*)qrelT;
  for (int i = tid; i < 2048; i += 256) rvT[i] = f2bf(relv[((i & 31) << 6) + (i >> 5)]);
  __syncthreads();

  // acc += Pband[q][r] * rvT[d][r]  (band + low), unnormalized
#pragma unroll
  for (int ks2 = 0; ks2 < 2; ++ks2) {
    bf16x8 pf = *(const bf16x8*)(Pband + (qloc << 5) + (ks2 << 4) + (hi << 3));
    bf16x8 rv0 = *(const bf16x8*)(rvT + (c32 << 5) + (ks2 << 4) + (hi << 3));
    bf16x8 rv1 = *(const bf16x8*)(rvT + ((32 + c32) << 5) + (ks2 << 4) + (hi << 3));
    acc0 = MFMA32(pf, rv0, acc0);
    acc1 = MFMA32(pf, rv1, acc1);
  }

  const int b = bh >> 3, h = bh & 7;
  const float rvA = rv32S[c32], rvB = rv32S[32 + c32];
#pragma unroll
  for (int r = 0; r < 16; ++r) {
    int qw = wavebase + (r & 3) + ((r >> 2) << 3) + (hi << 2);
    float2 nh = normS[qw];
    size_t orow = ((((size_t)b << 10) + (qbase + qw)) << 9) + (h << 6);
    Xout[orow + c32]      = f2bf((acc0[r] + nh.y * rvA) * nh.x);
    Xout[orow + 32 + c32] = f2bf((acc1[r] + nh.y * rvB) * nh.x);
  }
}

// ---------------- launch ----------------
extern "C" void kernel_launch(void* const* d_in, const int* in_sizes, int n_in,
                              void* d_out, int out_size, void* d_ws, size_t ws_size,
                              hipStream_t stream) {
  (void)in_sizes; (void)n_in; (void)out_size; (void)ws_size;
  const float* query = (const float*)d_in[0];
  const float* key   = (const float*)d_in[1];
  const float* value = (const float*)d_in[2];
  const float* Wq = (const float*)d_in[3];
  const float* bq = (const float*)d_in[4];
  const float* Wk = (const float*)d_in[5];
  const float* bk = (const float*)d_in[6];
  const float* Wv = (const float*)d_in[7];
  const float* bv = (const float*)d_in[8];
  const float* Wo = (const float*)d_in[9];
  const float* bo = (const float*)d_in[10];
  const float* relk = (const float*)d_in[11];
  const float* relv = (const float*)d_in[12];

  char* ws = (char*)d_ws;
  u16*   Xq    = (u16*)(ws + 0);
  u16*   Xk    = (u16*)(ws + 8388608);
  u16*   Xv    = (u16*)(ws + 16777216);
  u16*   Wqb   = (u16*)(ws + 25165824);
  u16*   Wkb   = (u16*)(ws + 25690112);
  u16*   Wvb   = (u16*)(ws + 26214400);
  u16*   Wob   = (u16*)(ws + 26738688);
  u16*   relkb = (u16*)(ws + 27262976);   // 33*64 bf16
  u16*   Qh    = (u16*)(ws + 27271168);
  u16*   Kh    = (u16*)(ws + 35659776);
  u16*   Vt    = (u16*)(ws + 52436992);
  u16*   Xout  = (u16*)(ws + 70262784);

  convAll<<<13315, 256, 0, stream>>>(query, key, value, Wq, Wk, Wv, Wo, relk,
                                     Xq, Xk, Xv, Wqb, Wkb, Wvb, Wob, relkb);
  qkv_gemm<<<768, 256, 0, stream>>>(Xq, Xk, Xv, Wqb, Wkb, Wvb, bq, bk, bv, Qh, Kh, Vt);
  flash_kernel<<<512, 256, 0, stream>>>(Qh, Kh, Vt, relkb, relv, Xout);
  gemm_out<<<256, 256, 0, stream>>>(Xout, Wob, bo, (float*)d_out);
}

// Round 10
// 104.920 us; speedup vs baseline: 1.2184x; 1.2184x over previous
//
#include <hip/hip_runtime.h>

typedef unsigned short u16;
typedef float f32x4 __attribute__((ext_vector_type(4)));
typedef __bf16 bf16x8 __attribute__((ext_vector_type(8)));

#define MFMA16(a, b, c) __builtin_amdgcn_mfma_f32_16x16x32_bf16((a), (b), (c), 0, 0, 0)

#define B_ 8
#define H_ 8
#define S_ 1024

__device__ __forceinline__ u16 f2bf(float f) {
  unsigned u = __float_as_uint(f);
  return (u16)((u + 0x7fffu + ((u >> 16) & 1u)) >> 16);
}
// pack 2 f32 -> 2 bf16 in one instr (dst.lo = a, dst.hi = b)
__device__ __forceinline__ unsigned cvtpk(float a, float b) {
  unsigned r;
  asm("v_cvt_pk_bf16_f32 %0, %1, %2" : "=v"(r) : "v"(a), "v"(b));
  return r;
}
// async global->LDS, 16B per lane. LDS dest = wave-uniform base + lane*16.
__device__ __forceinline__ void gload16(const void* g, void* l) {
  __builtin_amdgcn_global_load_lds((__attribute__((address_space(1))) const void*)g,
                                   (__attribute__((address_space(3))) void*)l, 16, 0, 0);
}

// ---------------- all fp32->bf16 converts in one dispatch ----------------
__global__ void __launch_bounds__(256) convAll(const float* __restrict__ q, const float* __restrict__ k,
                                               const float* __restrict__ v, const float* __restrict__ Wq,
                                               const float* __restrict__ Wk, const float* __restrict__ Wv,
                                               const float* __restrict__ Wo, const float* __restrict__ relk,
                                               u16* __restrict__ dq, u16* __restrict__ dk, u16* __restrict__ dv,
                                               u16* __restrict__ dWq, u16* __restrict__ dWk, u16* __restrict__ dWv,
                                               u16* __restrict__ dWo, u16* __restrict__ drelk) {
  const int bid = blockIdx.x;
  const float* s; u16* d; size_t off;
  if (bid < 12288) {
    size_t i4 = (size_t)bid * 256 + threadIdx.x;   // 3*1048576 float4s
    int tsel = (int)(i4 >> 20);
    off = (i4 & 1048575) << 2;
    s = tsel == 0 ? q : (tsel == 1 ? k : v);
    d = tsel == 0 ? dq : (tsel == 1 ? dk : dv);
  } else {
    size_t i = ((size_t)(bid - 12288) * 256 + threadIdx.x) << 2;
    if (i >= 1050688) return; // 4*262144 + 33*64
    if (i < 262144)       { s = Wq; d = dWq; off = i; }
    else if (i < 524288)  { s = Wk; d = dWk; off = i - 262144; }
    else if (i < 786432)  { s = Wv; d = dWv; off = i - 524288; }
    else if (i < 1048576) { s = Wo; d = dWo; off = i - 786432; }
    else                  { s = relk; d = drelk; off = i - 1048576; }
  }
  float4 f = *(const float4*)(s + off);
  uint2 o;
  o.x = cvtpk(f.x, f.y);
  o.y = cvtpk(f.z, f.w);
  *(uint2*)(d + off) = o;
}

// ---------------- fused Q/K/V projection GEMM (768 blocks) ----------------
// seg 0/1: Q/K -> bf16 ROW-MAJOR [8192][512] (swapped-MFMA epilogue, packed uint2 stores)
// seg 2:   V -> transposed head-split [B*H, 64, S] (unswapped, packed along s)
__global__ void __launch_bounds__(256) qkv_gemm(const u16* __restrict__ Xq, const u16* __restrict__ Xk,
                                                const u16* __restrict__ Xv, const u16* __restrict__ Wqb,
                                                const u16* __restrict__ Wkb, const u16* __restrict__ Wvb,
                                                const float* __restrict__ bq, const float* __restrict__ bk,
                                                const float* __restrict__ bv, u16* __restrict__ Qh,
                                                u16* __restrict__ Kh, u16* __restrict__ Vt) {
  __shared__ u16 As[128 * 64];
  __shared__ u16 Bs[128 * 64];
  const int seg = blockIdx.x >> 8, bid = blockIdx.x & 255;
  const u16* A = seg == 0 ? Xq : (seg == 1 ? Xk : Xv);
  const u16* W = seg == 0 ? Wqb : (seg == 1 ? Wkb : Wvb);
  const float* bias = seg == 0 ? bq : (seg == 1 ? bk : bv);
  const int tid = threadIdx.x, lane = tid & 63, wid = tid >> 6;
  const int c = lane & 15, g = lane >> 4;
  const int bm = bid >> 2, bn = bid & 3;
  const int m0 = bm << 7, n0 = bn << 7;
  const int wrow = (wid >> 1) << 6, wcol = (wid & 1) << 6;

  const f32x4 ZF = {0.f, 0.f, 0.f, 0.f};
  f32x4 acc[4][4];
#pragma unroll
  for (int i = 0; i < 4; ++i)
#pragma unroll
    for (int j = 0; j < 4; ++j) acc[i][j] = ZF;

  for (int kt = 0; kt < 512; kt += 64) {
    __syncthreads();
#pragma unroll
    for (int i = 0; i < 4; ++i) {
      int Lb = ((wid << 2) | i) << 10;
      int L = Lb + lane * 16;
      int row = L >> 7;                                 // 0..127
      int off = (L & 127) ^ ((row & 7) << 4);           // pre-swizzled source
      gload16((const char*)A + ((((size_t)(m0 + row)) << 9) + kt) * 2 + off, (char*)As + Lb);
      gload16((const char*)W + ((((size_t)(n0 + row)) << 9) + kt) * 2 + off, (char*)Bs + Lb);
    }
    __syncthreads();
#pragma unroll
    for (int kk = 0; kk < 2; ++kk) {
      bf16x8 af[4], bfr[4];
#pragma unroll
      for (int rt = 0; rt < 4; ++rt) {
        int row = wrow + (rt << 4) + c;
        af[rt] = *(const bf16x8*)((const char*)As + row * 128 + (((kk << 6) | (g << 4)) ^ ((row & 7) << 4)));
      }
#pragma unroll
      for (int ct = 0; ct < 4; ++ct) {
        int row = wcol + (ct << 4) + c;
        bfr[ct] = *(const bf16x8*)((const char*)Bs + row * 128 + (((kk << 6) | (g << 4)) ^ ((row & 7) << 4)));
      }
      if (seg == 2) {
#pragma unroll
        for (int rt = 0; rt < 4; ++rt)
#pragma unroll
          for (int ct = 0; ct < 4; ++ct) acc[rt][ct] = MFMA16(af[rt], bfr[ct], acc[rt][ct]);
      } else {
        // swapped: acc = C^T tile (cols = m, rows = n) -> packed row-major stores
#pragma unroll
        for (int rt = 0; rt < 4; ++rt)
#pragma unroll
          for (int ct = 0; ct < 4; ++ct) acc[rt][ct] = MFMA16(bfr[ct], af[rt], acc[rt][ct]);
      }
    }
  }

  if (seg == 2) {
#pragma unroll
    for (int rt = 0; rt < 4; ++rt)
#pragma unroll
      for (int ct = 0; ct < 4; ++ct) {
        int n = n0 + wcol + (ct << 4) + c;
        float bv2 = bias[n];
        int b2 = m0 >> 10;
        int sbase = (m0 & 1023) + wrow + (rt << 4) + (g << 2);
        int h2 = n >> 6, d2 = n & 63;
        uint2 o;
        o.x = cvtpk(acc[rt][ct][0] + bv2, acc[rt][ct][1] + bv2);
        o.y = cvtpk(acc[rt][ct][2] + bv2, acc[rt][ct][3] + bv2);
        *(uint2*)(Vt + ((((size_t)((b2 << 3) + h2) << 6) + d2) << 10) + sbase) = o;
      }
  } else {
    u16* out = seg == 0 ? Qh : Kh;
#pragma unroll
    for (int rt = 0; rt < 4; ++rt)
#pragma unroll
      for (int ct = 0; ct < 4; ++ct) {
        int m = m0 + wrow + (rt << 4) + c;
        int nb = n0 + wcol + (ct << 4) + (g << 2);
        float4 bv4 = *(const float4*)(bias + nb);
        uint2 o;
        o.x = cvtpk(acc[rt][ct][0] + bv4.x, acc[rt][ct][1] + bv4.y);
        o.y = cvtpk(acc[rt][ct][2] + bv4.z, acc[rt][ct][3] + bv4.w);
        *(uint2*)(out + ((size_t)m << 9) + nb) = o;
      }
  }
}

// ---------------- output GEMM (swapped): C fp32 [M][512], packed float4 stores ----------------
__global__ void __launch_bounds__(256) gemm_out(const u16* __restrict__ A, const u16* __restrict__ W,
                                                const float* __restrict__ bias, float* __restrict__ out) {
  __shared__ u16 As[128 * 64];
  __shared__ u16 Bs[128 * 64];
  const int tid = threadIdx.x, lane = tid & 63, wid = tid >> 6;
  const int c = lane & 15, g = lane >> 4;
  const int bm = blockIdx.x >> 2, bn = blockIdx.x & 3;
  const int m0 = bm << 7, n0 = bn << 7;
  const int wrow = (wid >> 1) << 6, wcol = (wid & 1) << 6;

  const f32x4 ZF = {0.f, 0.f, 0.f, 0.f};
  f32x4 acc[4][4];
#pragma unroll
  for (int i = 0; i < 4; ++i)
#pragma unroll
    for (int j = 0; j < 4; ++j) acc[i][j] = ZF;

  for (int kt = 0; kt < 512; kt += 64) {
    __syncthreads();
#pragma unroll
    for (int i = 0; i < 4; ++i) {
      int Lb = ((wid << 2) | i) << 10;
      int L = Lb + lane * 16;
      int row = L >> 7;
      int off = (L & 127) ^ ((row & 7) << 4);
      gload16((const char*)A + ((((size_t)(m0 + row)) << 9) + kt) * 2 + off, (char*)As + Lb);
      gload16((const char*)W + ((((size_t)(n0 + row)) << 9) + kt) * 2 + off, (char*)Bs + Lb);
    }
    __syncthreads();
#pragma unroll
    for (int kk = 0; kk < 2; ++kk) {
      bf16x8 af[4], bfr[4];
#pragma unroll
      for (int rt = 0; rt < 4; ++rt) {
        int row = wrow + (rt << 4) + c;
        af[rt] = *(const bf16x8*)((const char*)As + row * 128 + (((kk << 6) | (g << 4)) ^ ((row & 7) << 4)));
      }
#pragma unroll
      for (int ct = 0; ct < 4; ++ct) {
        int row = wcol + (ct << 4) + c;
        bfr[ct] = *(const bf16x8*)((const char*)Bs + row * 128 + (((kk << 6) | (g << 4)) ^ ((row & 7) << 4)));
      }
#pragma unroll
      for (int rt = 0; rt < 4; ++rt)
#pragma unroll
        for (int ct = 0; ct < 4; ++ct) acc[rt][ct] = MFMA16(bfr[ct], af[rt], acc[rt][ct]);  // C^T
    }
  }

#pragma unroll
  for (int rt = 0; rt < 4; ++rt)
#pragma unroll
    for (int ct = 0; ct < 4; ++ct) {
      int m = m0 + wrow + (rt << 4) + c;
      int nb = n0 + wcol + (ct << 4) + (g << 2);
      float4 bv4 = *(const float4*)(bias + nb);
      float4 o;
      o.x = acc[rt][ct][0] + bv4.x;
      o.y = acc[rt][ct][1] + bv4.y;
      o.z = acc[rt][ct][2] + bv4.z;
      o.w = acc[rt][ct][3] + bv4.w;
      *(float4*)(out + ((size_t)m << 9) + nb) = o;
    }
}

// ---------------- flash attention: round-4 structure (8 waves, 128 q, fused qrel + rel-V) ----------------
// Q/K now ROW-MAJOR [8192][512]; lane (c,g) of wave wid owns q = qbase + wid*16 + c everywhere.
__global__ void __launch_bounds__(512) flash_kernel(const u16* __restrict__ Qh, const u16* __restrict__ Kh,
                                                    const u16* __restrict__ Vt, const u16* __restrict__ relkb,
                                                    const float* __restrict__ relv, u16* __restrict__ Xout) {
  __shared__ u16 Ks[2][64 * 64];
  __shared__ u16 Vs[2][64 * 64];
  __shared__ u16 Ps[128 * 64];
  __shared__ float qrelS[128 * 34];   // exp2-domain bias table; overlaid by rvT in epilogue
  __shared__ u16 Pband[128 * 32];     // unnormalized bf16 band probs; slot 0 = low bucket
  __shared__ float rv32S[64];

  const int tid = threadIdx.x, lane = tid & 63, wid = tid >> 6;
  const int c = lane & 15, g = lane >> 4;
  // XCD swizzle: 8 chunks of 64 consecutive blocks
  const int swz = ((blockIdx.x & 7) << 6) | (blockIdx.x >> 3);
  const int bh = swz >> 3, qt = swz & 7;
  const int qbase = qt << 7;
  const int b = bh >> 3, h = bh & 7;
  const int qloc = (wid << 4) + c;
  const float K1 = 0.51013619f;   // (1/sqrt(8)) * log2(e)
  const float C0 = 24.0f;

  // row-major base offsets (bytes for K staging, u16 for Q reads)
  const size_t Kbyte = ((size_t)b << 20) + ((size_t)h << 7);     // b*1024 rows * 1024B + h*128B
  const u16* Qrow = Qh + ((size_t)b << 19) + (h << 6);           // b*1024*512 + h*64 (u16)

  // Q fragments (issue loads first)
  bf16x8 qa[2];
  {
    const u16* qptr = Qrow + ((size_t)(qbase + qloc) << 9);
    qa[0] = *(const bf16x8*)(qptr + (g << 3));
    qa[1] = *(const bf16x8*)(qptr + 32 + (g << 3));
  }

#define STAGE(buf, kt_) do { \
    const int k64_ = (kt_) << 6; \
    int L_ = (wid << 10) + lane * 16; \
    int row_ = L_ >> 7; \
    int off_ = (L_ & 127) ^ ((row_ & 7) << 4); \
    gload16((const char*)Kh + Kbyte + ((size_t)(k64_ + row_) << 10) + off_, (char*)Ks[buf] + (wid << 10)); \
    gload16((const char*)Vt + ((((size_t)bh << 6) + row_) << 11) + (k64_ << 1) + off_, (char*)Vs[buf] + (wid << 10)); \
  } while (0)

  STAGE(0, 0);

  // zero Pband (8192B), load rv32
  ((uint4*)Pband)[tid] = uint4{0, 0, 0, 0};
  if (tid < 64) rv32S[tid] = relv[2048 + tid];

  // qrel in prologue: qrelS[q][r] = (Q[q,:].relk[r,:]) * K1 - C0, via 6 MFMAs per wave
  {
    const f32x4 ZF = {0.f, 0.f, 0.f, 0.f};
#pragma unroll
    for (int t = 0; t < 3; ++t) {
      int rr = t * 16 + c; if (rr > 32) rr = 32;
      f32x4 qr = ZF;
#pragma unroll
      for (int kk = 0; kk < 2; ++kk) {
        bf16x8 ar = *(const bf16x8*)(relkb + (rr << 6) + (kk << 5) + (g << 3));
        qr = MFMA16(ar, qa[kk], qr);
      }
#pragma unroll
      for (int j = 0; j < 4; ++j) {
        int r = t * 16 + (g << 2) + j;
        if (r < 33) qrelS[qloc * 34 + r] = qr[j] * K1 - C0;
      }
    }
  }
  __syncthreads();   // covers STAGE(0), Pband init, qrelS, rv32S

  const float bias_lo = qrelS[qloc * 34 + 0];
  const float bias_hi = qrelS[qloc * 34 + 32];

  // hoisted loop-invariant LDS byte offsets
  int koff[4][2], voff[4][2], poffw[4];
#pragma unroll
  for (int t = 0; t < 4; ++t) {
#pragma unroll
    for (int kk = 0; kk < 2; ++kk)
      koff[t][kk] = ((t << 4) + c) * 128 + ((((kk << 6) | (g << 4))) ^ ((c & 7) << 4));
#pragma unroll
    for (int h2 = 0; h2 < 2; ++h2)
      voff[t][h2] = ((t << 4) + c) * 128 + ((((h2 << 6) | (g << 4))) ^ ((c & 7) << 4));
    poffw[t] = qloc * 128 + (((t << 5) | (g << 3)) ^ ((c & 7) << 4));
  }
  const int pr0 = qloc * 128 + ((g << 4) ^ ((c & 7) << 4));
  const int pr1 = pr0 ^ 64;

  const f32x4 ZF = {0.f, 0.f, 0.f, 0.f};
  f32x4 acc[4] = {ZF, ZF, ZF, ZF};
  float lsum = 0.f, lowsum = 0.f, psum = 0.f;

  for (int kt = 0; kt < 16; ++kt) {
    const int cur = kt & 1;
    if (kt < 15) STAGE(cur ^ 1, kt + 1);   // prefetch into other buffer

    // QK^T swapped: sa[t][j] = S[k = kt*64 + t*16 + g*4 + j][q = own]
    f32x4 sa[4];
#pragma unroll
    for (int t = 0; t < 4; ++t) {
      sa[t] = ZF;
#pragma unroll
      for (int kk = 0; kk < 2; ++kk) {
        bf16x8 bk = *(const bf16x8*)((const char*)Ks + (cur << 13) + koff[t][kk]);
        sa[t] = MFMA16(bk, qa[kk], sa[t]);
      }
    }

    const int D0 = (kt << 6) - qbase;
    float p[4][4];
    if (D0 >= 192) {            // all dlt >= 17: high bucket
      float ps4[4] = {0.f, 0.f, 0.f, 0.f};
#pragma unroll
      for (int t = 0; t < 4; ++t)
#pragma unroll
        for (int j = 0; j < 4; ++j) {
          float pe = __builtin_amdgcn_exp2f(fmaf(sa[t][j], K1, bias_hi));
          p[t][j] = pe; ps4[j] += pe;
        }
      lsum += (ps4[0] + ps4[1]) + (ps4[2] + ps4[3]);
    } else if (D0 <= -128) {    // all dlt <= -17: low bucket
      float ps4[4] = {0.f, 0.f, 0.f, 0.f};
#pragma unroll
      for (int t = 0; t < 4; ++t)
#pragma unroll
        for (int j = 0; j < 4; ++j) {
          float pe = __builtin_amdgcn_exp2f(fmaf(sa[t][j], K1, bias_lo));
          p[t][j] = pe; ps4[j] += pe;
        }
      float t0 = (ps4[0] + ps4[1]) + (ps4[2] + ps4[3]);
      lsum += t0; lowsum += t0;
    } else {                    // boundary tiles (4 of 16)
#pragma unroll
      for (int t = 0; t < 4; ++t)
#pragma unroll
        for (int j = 0; j < 4; ++j) {
          int dlt = D0 + (t << 4) + (g << 2) + j - qloc;
          int idx = dlt < -16 ? 0 : (dlt > 16 ? 32 : dlt + 16);
          float pe = __builtin_amdgcn_exp2f(fmaf(sa[t][j], K1, qrelS[qloc * 34 + idx]));
          p[t][j] = pe;
          lsum += pe;
          if (dlt <= -16) lowsum += pe;
          else if (dlt < 16) { psum += pe; Pband[(qloc << 5) + dlt + 16] = f2bf(pe); }
        }
    }

    // P -> LDS (own row), then PV swapped: acc[dt][j] = O[d = dt*16+g*4+j][q = own]
#pragma unroll
    for (int t = 0; t < 4; ++t) {
      uint2 pk;
      pk.x = cvtpk(p[t][0], p[t][1]);
      pk.y = cvtpk(p[t][2], p[t][3]);
      *(uint2*)((char*)Ps + poffw[t]) = pk;
    }
    bf16x8 pb0 = *(const bf16x8*)((const char*)Ps + pr0);
    bf16x8 pb1 = *(const bf16x8*)((const char*)Ps + pr1);
#pragma unroll
    for (int dt = 0; dt < 4; ++dt) {
      bf16x8 av0 = *(const bf16x8*)((const char*)Vs + (cur << 13) + voff[dt][0]);
      bf16x8 av1 = *(const bf16x8*)((const char*)Vs + (cur << 13) + voff[dt][1]);
      acc[dt] = MFMA16(av0, pb0, acc[dt]);
      acc[dt] = MFMA16(av1, pb1, acc[dt]);
    }
    __syncthreads();   // drains prefetch + protects dbuf swap
  }

  // ---- epilogue ----
  lsum += __shfl_xor(lsum, 16);   lsum += __shfl_xor(lsum, 32);
  lowsum += __shfl_xor(lowsum, 16); lowsum += __shfl_xor(lowsum, 32);
  psum += __shfl_xor(psum, 16);   psum += __shfl_xor(psum, 32);
  const float inv = 1.f / lsum;
  const float hsum = lsum - lowsum - psum;   // unnormalized high-bucket mass

  if (g == 0) Pband[qloc << 5] = f2bf(lowsum);   // low bucket slot (unnormalized)

  // overlay rv^T (bf16 [d][r=0..31]) into dead qrelS
  u16* rvT = (u16*)qrelS;
  for (int i = tid; i < 4096; i += 512) rvT[i] = f2bf(relv[((i & 31) << 6) + (i >> 5)]);
  __syncthreads();

  // acc += rv^T[d][r] * Pband[r][q]  (band + low), all unnormalized
  bf16x8 pb2 = *(const bf16x8*)((const u16*)Pband + (qloc << 5) + (g << 3));
#pragma unroll
  for (int dt = 0; dt < 4; ++dt) {
    bf16x8 av = *(const bf16x8*)(rvT + (((dt << 4) + c) << 5) + (g << 3));
    acc[dt] = MFMA16(av, pb2, acc[dt]);
  }

  const int q = qbase + qloc;
  u16* xb = Xout + ((((size_t)b << 10) + q) << 9) + (h << 6);
#pragma unroll
  for (int dt = 0; dt < 4; ++dt) {
    int d0 = (dt << 4) + (g << 2);
    float v0 = (acc[dt][0] + hsum * rv32S[d0 + 0]) * inv;
    float v1 = (acc[dt][1] + hsum * rv32S[d0 + 1]) * inv;
    float v2 = (acc[dt][2] + hsum * rv32S[d0 + 2]) * inv;
    float v3 = (acc[dt][3] + hsum * rv32S[d0 + 3]) * inv;
    uint2 o;
    o.x = cvtpk(v0, v1);
    o.y = cvtpk(v2, v3);
    *(uint2*)(xb + d0) = o;
  }
#undef STAGE
}

// ---------------- launch ----------------
extern "C" void kernel_launch(void* const* d_in, const int* in_sizes, int n_in,
                              void* d_out, int out_size, void* d_ws, size_t ws_size,
                              hipStream_t stream) {
  (void)in_sizes; (void)n_in; (void)out_size; (void)ws_size;
  const float* query = (const float*)d_in[0];
  const float* key   = (const float*)d_in[1];
  const float* value = (const float*)d_in[2];
  const float* Wq = (const float*)d_in[3];
  const float* bq = (const float*)d_in[4];
  const float* Wk = (const float*)d_in[5];
  const float* bk = (const float*)d_in[6];
  const float* Wv = (const float*)d_in[7];
  const float* bv = (const float*)d_in[8];
  const float* Wo = (const float*)d_in[9];
  const float* bo = (const float*)d_in[10];
  const float* relk = (const float*)d_in[11];
  const float* relv = (const float*)d_in[12];

  char* ws = (char*)d_ws;
  u16*   Xq    = (u16*)(ws + 0);
  u16*   Xk    = (u16*)(ws + 8388608);
  u16*   Xv    = (u16*)(ws + 16777216);
  u16*   Wqb   = (u16*)(ws + 25165824);
  u16*   Wkb   = (u16*)(ws + 25690112);
  u16*   Wvb   = (u16*)(ws + 26214400);
  u16*   Wob   = (u16*)(ws + 26738688);
  u16*   relkb = (u16*)(ws + 27262976);   // 33*64 bf16
  u16*   Qh    = (u16*)(ws + 27271168);
  u16*   Kh    = (u16*)(ws + 35659776);
  u16*   Vt    = (u16*)(ws + 52436992);
  u16*   Xout  = (u16*)(ws + 70262784);

  convAll<<<13315, 256, 0, stream>>>(query, key, value, Wq, Wk, Wv, Wo, relk,
                                     Xq, Xk, Xv, Wqb, Wkb, Wvb, Wob, relkb);
  qkv_gemm<<<768, 256, 0, stream>>>(Xq, Xk, Xv, Wqb, Wkb, Wvb, bq, bk, bv, Qh, Kh, Vt);
  flash_kernel<<<512, 512, 0, stream>>>(Qh, Kh, Vt, relkb, relv, Xout);
  gemm_out<<<256, 256, 0, stream>>>(Xout, Wob, bo, (float*)d_out);
}

// Round 11
// 102.062 us; speedup vs baseline: 1.2525x; 1.0280x over previous
//
#include <hip/hip_runtime.h>

typedef unsigned short u16;
typedef float f32x4 __attribute__((ext_vector_type(4)));
typedef __bf16 bf16x8 __attribute__((ext_vector_type(8)));

#define MFMA16(a, b, c) __builtin_amdgcn_mfma_f32_16x16x32_bf16((a), (b), (c), 0, 0, 0)

#define B_ 8
#define H_ 8
#define S_ 1024

__device__ __forceinline__ u16 f2bf(float f) {
  unsigned u = __float_as_uint(f);
  return (u16)((u + 0x7fffu + ((u >> 16) & 1u)) >> 16);
}
// pack 2 f32 -> 2 bf16 in one instr (dst.lo = a, dst.hi = b)
__device__ __forceinline__ unsigned cvtpk(float a, float b) {
  unsigned r;
  asm("v_cvt_pk_bf16_f32 %0, %1, %2" : "=v"(r) : "v"(a), "v"(b));
  return r;
}
// async global->LDS, 16B per lane. LDS dest = wave-uniform base + lane*16.
__device__ __forceinline__ void gload16(const void* g, void* l) {
  __builtin_amdgcn_global_load_lds((__attribute__((address_space(1))) const void*)g,
                                   (__attribute__((address_space(3))) void*)l, 16, 0, 0);
}

// ---------------- weights + relk fp32->bf16 (3.15 MB only) ----------------
__global__ void __launch_bounds__(256) convW(const float* __restrict__ s0, const float* __restrict__ s1,
                                             const float* __restrict__ s2, const float* __restrict__ s3,
                                             const float* __restrict__ s4,
                                             u16* __restrict__ d0, u16* __restrict__ d1, u16* __restrict__ d2,
                                             u16* __restrict__ d3, u16* __restrict__ d4) {
  size_t i = ((size_t)blockIdx.x * 256 + threadIdx.x) << 2;
  if (i >= 1050688) return; // 4*262144 + 33*64
  const float* s; u16* d; size_t off;
  if (i < 262144)       { s = s0; d = d0; off = i; }
  else if (i < 524288)  { s = s1; d = d1; off = i - 262144; }
  else if (i < 786432)  { s = s2; d = d2; off = i - 524288; }
  else if (i < 1048576) { s = s3; d = d3; off = i - 786432; }
  else                  { s = s4; d = d4; off = i - 1048576; }
  float4 f = *(const float4*)(s + off);
  uint2 o;
  o.x = cvtpk(f.x, f.y);
  o.y = cvtpk(f.z, f.w);
  *(uint2*)(d + off) = o;
}

// ---------------- fused Q/K/V projection GEMM (768 blocks), A read directly from f32 ----------------
// seg 0: Q -> bf16 head-split [B,H,S,64]; seg 1: K same; seg 2: V -> transposed [B*H,64,S].
// A-tile staging: reg-stage f32 -> cvtpk -> ds_write_b128 into the same linear-swizzled slots.
__global__ void __launch_bounds__(256) qkv_gemm(const float* __restrict__ Aq, const float* __restrict__ Ak,
                                                const float* __restrict__ Av, const u16* __restrict__ Wqb,
                                                const u16* __restrict__ Wkb, const u16* __restrict__ Wvb,
                                                const float* __restrict__ bq, const float* __restrict__ bk,
                                                const float* __restrict__ bv, u16* __restrict__ Qh,
                                                u16* __restrict__ Kh, u16* __restrict__ Vt) {
  __shared__ u16 As[128 * 64];
  __shared__ u16 Bs[128 * 64];
  const int seg = blockIdx.x >> 8, bid = blockIdx.x & 255;
  const float* Af = seg == 0 ? Aq : (seg == 1 ? Ak : Av);
  const u16* W = seg == 0 ? Wqb : (seg == 1 ? Wkb : Wvb);
  const float* bias = seg == 0 ? bq : (seg == 1 ? bk : bv);
  const int tid = threadIdx.x, lane = tid & 63, wid = tid >> 6;
  const int c = lane & 15, g = lane >> 4;
  const int bm = bid >> 2, bn = bid & 3;
  const int m0 = bm << 7, n0 = bn << 7;
  const int wrow = (wid >> 1) << 6, wcol = (wid & 1) << 6;

  const f32x4 ZF = {0.f, 0.f, 0.f, 0.f};
  f32x4 acc[4][4];
#pragma unroll
  for (int i = 0; i < 4; ++i)
#pragma unroll
    for (int j = 0; j < 4; ++j) acc[i][j] = ZF;

  for (int kt = 0; kt < 512; kt += 64) {
    __syncthreads();
#pragma unroll
    for (int i = 0; i < 4; ++i) {
      int Lb = ((wid << 2) | i) << 10;
      int L = Lb + lane * 16;
      int row = L >> 7;                                 // 0..127
      int off = (L & 127) ^ ((row & 7) << 4);           // swizzled byte offset (bf16 domain)
      // A: load 8 f32 from true source position, convert, write to linear LDS slot
      const float* ap = Af + (((size_t)(m0 + row)) << 9) + kt + (off >> 1);
      float4 a0 = *(const float4*)ap;
      float4 a1 = *(const float4*)(ap + 4);
      uint4 aw;
      aw.x = cvtpk(a0.x, a0.y); aw.y = cvtpk(a0.z, a0.w);
      aw.z = cvtpk(a1.x, a1.y); aw.w = cvtpk(a1.z, a1.w);
      *(uint4*)((char*)As + L) = aw;
      // W: bf16, pre-swizzled async global->LDS
      gload16((const char*)W + ((((size_t)(n0 + row)) << 9) + kt) * 2 + off, (char*)Bs + Lb);
    }
    __syncthreads();
#pragma unroll
    for (int kk = 0; kk < 2; ++kk) {
      bf16x8 af[4], bfr[4];
#pragma unroll
      for (int rt = 0; rt < 4; ++rt) {
        int row = wrow + (rt << 4) + c;
        af[rt] = *(const bf16x8*)((const char*)As + row * 128 + (((kk << 6) | (g << 4)) ^ ((row & 7) << 4)));
      }
#pragma unroll
      for (int ct = 0; ct < 4; ++ct) {
        int row = wcol + (ct << 4) + c;
        bfr[ct] = *(const bf16x8*)((const char*)Bs + row * 128 + (((kk << 6) | (g << 4)) ^ ((row & 7) << 4)));
      }
#pragma unroll
      for (int rt = 0; rt < 4; ++rt)
#pragma unroll
        for (int ct = 0; ct < 4; ++ct) acc[rt][ct] = MFMA16(af[rt], bfr[ct], acc[rt][ct]);
    }
  }

#pragma unroll
  for (int rt = 0; rt < 4; ++rt)
#pragma unroll
    for (int ct = 0; ct < 4; ++ct) {
      int n = n0 + wcol + (ct << 4) + c;
      float bv2 = bias[n];
      if (seg == 2) {
        int b2 = m0 >> 10;
        int sbase = (m0 & 1023) + wrow + (rt << 4) + (g << 2);
        int h2 = n >> 6, d2 = n & 63;
        uint2 o;
        o.x = cvtpk(acc[rt][ct][0] + bv2, acc[rt][ct][1] + bv2);
        o.y = cvtpk(acc[rt][ct][2] + bv2, acc[rt][ct][3] + bv2);
        *(uint2*)(Vt + ((((size_t)((b2 << 3) + h2) << 6) + d2) << 10) + sbase) = o;
      } else {
        u16* out = seg == 0 ? Qh : Kh;
#pragma unroll
        for (int r = 0; r < 4; ++r) {
          int m = m0 + wrow + (rt << 4) + (g << 2) + r;
          int b = m >> 10, s = m & 1023, h = n >> 6, d = n & 63;
          out[(((((size_t)(b * H_ + h)) << 10) + s) << 6) + d] = f2bf(acc[rt][ct][r] + bv2);
        }
      }
    }
}

// ---------------- output GEMM: C fp32 [M][512] = A(bf16) @ W(bf16)^T + bias ----------------
__global__ void __launch_bounds__(256) gemm_out(const u16* __restrict__ A, const u16* __restrict__ W,
                                                const float* __restrict__ bias, float* __restrict__ out) {
  __shared__ u16 As[128 * 64];
  __shared__ u16 Bs[128 * 64];
  const int tid = threadIdx.x, lane = tid & 63, wid = tid >> 6;
  const int c = lane & 15, g = lane >> 4;
  const int bm = blockIdx.x >> 2, bn = blockIdx.x & 3;
  const int m0 = bm << 7, n0 = bn << 7;
  const int wrow = (wid >> 1) << 6, wcol = (wid & 1) << 6;

  const f32x4 ZF = {0.f, 0.f, 0.f, 0.f};
  f32x4 acc[4][4];
#pragma unroll
  for (int i = 0; i < 4; ++i)
#pragma unroll
    for (int j = 0; j < 4; ++j) acc[i][j] = ZF;

  for (int kt = 0; kt < 512; kt += 64) {
    __syncthreads();
#pragma unroll
    for (int i = 0; i < 4; ++i) {
      int Lb = ((wid << 2) | i) << 10;
      int L = Lb + lane * 16;
      int row = L >> 7;
      int off = (L & 127) ^ ((row & 7) << 4);
      gload16((const char*)A + ((((size_t)(m0 + row)) << 9) + kt) * 2 + off, (char*)As + Lb);
      gload16((const char*)W + ((((size_t)(n0 + row)) << 9) + kt) * 2 + off, (char*)Bs + Lb);
    }
    __syncthreads();
#pragma unroll
    for (int kk = 0; kk < 2; ++kk) {
      bf16x8 af[4], bfr[4];
#pragma unroll
      for (int rt = 0; rt < 4; ++rt) {
        int row = wrow + (rt << 4) + c;
        af[rt] = *(const bf16x8*)((const char*)As + row * 128 + (((kk << 6) | (g << 4)) ^ ((row & 7) << 4)));
      }
#pragma unroll
      for (int ct = 0; ct < 4; ++ct) {
        int row = wcol + (ct << 4) + c;
        bfr[ct] = *(const bf16x8*)((const char*)Bs + row * 128 + (((kk << 6) | (g << 4)) ^ ((row & 7) << 4)));
      }
#pragma unroll
      for (int rt = 0; rt < 4; ++rt)
#pragma unroll
        for (int ct = 0; ct < 4; ++ct) acc[rt][ct] = MFMA16(af[rt], bfr[ct], acc[rt][ct]);
    }
  }

#pragma unroll
  for (int rt = 0; rt < 4; ++rt)
#pragma unroll
    for (int ct = 0; ct < 4; ++ct) {
      int n = n0 + wcol + (ct << 4) + c;
      float bv = bias[n];
#pragma unroll
      for (int r = 0; r < 4; ++r) {
        int m = m0 + wrow + (rt << 4) + (g << 2) + r;
        out[(((size_t)m) << 9) + n] = acc[rt][ct][r] + bv;
      }
    }
}

// ---------------- flash attention: round-4 structure (8 waves, 128 q, fused qrel + rel-V) ----------------
// lane (c,g) of wave wid owns q = qbase + wid*16 + c everywhere.
__global__ void __launch_bounds__(512) flash_kernel(const u16* __restrict__ Qh, const u16* __restrict__ Kh,
                                                    const u16* __restrict__ Vt, const u16* __restrict__ relkb,
                                                    const float* __restrict__ relv, u16* __restrict__ Xout) {
  __shared__ u16 Ks[2][64 * 64];
  __shared__ u16 Vs[2][64 * 64];
  __shared__ u16 Ps[128 * 64];
  __shared__ float qrelS[128 * 34];   // exp2-domain bias table; overlaid by rvT in epilogue
  __shared__ u16 Pband[128 * 32];     // unnormalized bf16 band probs; slot 0 = low bucket
  __shared__ float rv32S[64];

  const int tid = threadIdx.x, lane = tid & 63, wid = tid >> 6;
  const int c = lane & 15, g = lane >> 4;
  // XCD swizzle: 8 chunks of 64 consecutive blocks
  const int swz = ((blockIdx.x & 7) << 6) | (blockIdx.x >> 3);
  const int bh = swz >> 3, qt = swz & 7;
  const int qbase = qt << 7;
  const size_t rowbase = ((size_t)bh) << 10;
  const int qloc = (wid << 4) + c;
  const float K1 = 0.51013619f;   // (1/sqrt(8)) * log2(e)
  const float C0 = 24.0f;

  // Q fragments (issue loads first)
  bf16x8 qa[2];
  {
    const u16* qptr = Qh + ((rowbase + qbase + qloc) << 6);
    qa[0] = *(const bf16x8*)(qptr + (g << 3));
    qa[1] = *(const bf16x8*)(qptr + 32 + (g << 3));
  }

#define STAGE(buf, kt_) do { \
    const int k64_ = (kt_) << 6; \
    int L_ = (wid << 10) + lane * 16; \
    int row_ = L_ >> 7; \
    int off_ = (L_ & 127) ^ ((row_ & 7) << 4); \
    gload16((const char*)Kh + ((rowbase + k64_ + row_) << 7) + off_, (char*)Ks[buf] + (wid << 10)); \
    gload16((const char*)Vt + ((((size_t)bh << 6) + row_) << 11) + (k64_ << 1) + off_, (char*)Vs[buf] + (wid << 10)); \
  } while (0)

  STAGE(0, 0);

  // zero Pband (8192B), load rv32
  ((uint4*)Pband)[tid] = uint4{0, 0, 0, 0};
  if (tid < 64) rv32S[tid] = relv[2048 + tid];

  // qrel in prologue: qrelS[q][r] = (Q[q,:].relk[r,:]) * K1 - C0, via 6 MFMAs per wave
  {
    const f32x4 ZF = {0.f, 0.f, 0.f, 0.f};
#pragma unroll
    for (int t = 0; t < 3; ++t) {
      int rr = t * 16 + c; if (rr > 32) rr = 32;
      f32x4 qr = ZF;
#pragma unroll
      for (int kk = 0; kk < 2; ++kk) {
        bf16x8 ar = *(const bf16x8*)(relkb + (rr << 6) + (kk << 5) + (g << 3));
        qr = MFMA16(ar, qa[kk], qr);
      }
#pragma unroll
      for (int j = 0; j < 4; ++j) {
        int r = t * 16 + (g << 2) + j;
        if (r < 33) qrelS[qloc * 34 + r] = qr[j] * K1 - C0;
      }
    }
  }
  __syncthreads();   // covers STAGE(0), Pband init, qrelS, rv32S

  const float bias_lo = qrelS[qloc * 34 + 0];
  const float bias_hi = qrelS[qloc * 34 + 32];

  // hoisted loop-invariant LDS byte offsets
  int koff[4][2], voff[4][2], poffw[4];
#pragma unroll
  for (int t = 0; t < 4; ++t) {
#pragma unroll
    for (int kk = 0; kk < 2; ++kk)
      koff[t][kk] = ((t << 4) + c) * 128 + ((((kk << 6) | (g << 4))) ^ ((c & 7) << 4));
#pragma unroll
    for (int h2 = 0; h2 < 2; ++h2)
      voff[t][h2] = ((t << 4) + c) * 128 + ((((h2 << 6) | (g << 4))) ^ ((c & 7) << 4));
    poffw[t] = qloc * 128 + (((t << 5) | (g << 3)) ^ ((c & 7) << 4));
  }
  const int pr0 = qloc * 128 + ((g << 4) ^ ((c & 7) << 4));
  const int pr1 = pr0 ^ 64;

  const f32x4 ZF = {0.f, 0.f, 0.f, 0.f};
  f32x4 acc[4] = {ZF, ZF, ZF, ZF};
  float lsum = 0.f, lowsum = 0.f, psum = 0.f;

  for (int kt = 0; kt < 16; ++kt) {
    const int cur = kt & 1;
    if (kt < 15) STAGE(cur ^ 1, kt + 1);   // prefetch into other buffer

    // QK^T swapped: sa[t][j] = S[k = kt*64 + t*16 + g*4 + j][q = own]
    f32x4 sa[4];
#pragma unroll
    for (int t = 0; t < 4; ++t) {
      sa[t] = ZF;
#pragma unroll
      for (int kk = 0; kk < 2; ++kk) {
        bf16x8 bk = *(const bf16x8*)((const char*)Ks + (cur << 13) + koff[t][kk]);
        sa[t] = MFMA16(bk, qa[kk], sa[t]);
      }
    }

    const int D0 = (kt << 6) - qbase;
    float p[4][4];
    if (D0 >= 192) {            // all dlt >= 17: high bucket
      float s = 0.f;
#pragma unroll
      for (int t = 0; t < 4; ++t)
#pragma unroll
        for (int j = 0; j < 4; ++j) {
          float pe = __builtin_amdgcn_exp2f(fmaf(sa[t][j], K1, bias_hi));
          p[t][j] = pe; s += pe;
        }
      lsum += s;
    } else if (D0 <= -128) {    // all dlt <= -17: low bucket
      float s = 0.f;
#pragma unroll
      for (int t = 0; t < 4; ++t)
#pragma unroll
        for (int j = 0; j < 4; ++j) {
          float pe = __builtin_amdgcn_exp2f(fmaf(sa[t][j], K1, bias_lo));
          p[t][j] = pe; s += pe;
        }
      lsum += s; lowsum += s;
    } else {                    // boundary tiles (4 of 16)
#pragma unroll
      for (int t = 0; t < 4; ++t)
#pragma unroll
        for (int j = 0; j < 4; ++j) {
          int dlt = D0 + (t << 4) + (g << 2) + j - qloc;
          int idx = dlt < -16 ? 0 : (dlt > 16 ? 32 : dlt + 16);
          float pe = __builtin_amdgcn_exp2f(fmaf(sa[t][j], K1, qrelS[qloc * 34 + idx]));
          p[t][j] = pe;
          lsum += pe;
          if (dlt <= -16) lowsum += pe;
          else if (dlt < 16) { psum += pe; Pband[(qloc << 5) + dlt + 16] = f2bf(pe); }
        }
    }

    // P -> LDS (own row), then PV swapped: acc[dt][j] = O[d = dt*16+g*4+j][q = own]
#pragma unroll
    for (int t = 0; t < 4; ++t) {
      uint2 pk;
      pk.x = cvtpk(p[t][0], p[t][1]);
      pk.y = cvtpk(p[t][2], p[t][3]);
      *(uint2*)((char*)Ps + poffw[t]) = pk;
    }
    bf16x8 pb0 = *(const bf16x8*)((const char*)Ps + pr0);
    bf16x8 pb1 = *(const bf16x8*)((const char*)Ps + pr1);
#pragma unroll
    for (int dt = 0; dt < 4; ++dt) {
      bf16x8 av0 = *(const bf16x8*)((const char*)Vs + (cur << 13) + voff[dt][0]);
      bf16x8 av1 = *(const bf16x8*)((const char*)Vs + (cur << 13) + voff[dt][1]);
      acc[dt] = MFMA16(av0, pb0, acc[dt]);
      acc[dt] = MFMA16(av1, pb1, acc[dt]);
    }
    __syncthreads();   // drains prefetch + protects dbuf swap
  }

  // ---- epilogue ----
  lsum += __shfl_xor(lsum, 16);   lsum += __shfl_xor(lsum, 32);
  lowsum += __shfl_xor(lowsum, 16); lowsum += __shfl_xor(lowsum, 32);
  psum += __shfl_xor(psum, 16);   psum += __shfl_xor(psum, 32);
  const float inv = 1.f / lsum;
  const float hsum = lsum - lowsum - psum;   // unnormalized high-bucket mass

  if (g == 0) Pband[qloc << 5] = f2bf(lowsum);   // low bucket slot (unnormalized)

  // overlay rv^T (bf16 [d][r=0..31]) into dead qrelS
  u16* rvT = (u16*)qrelS;
  for (int i = tid; i < 4096; i += 512) rvT[i] = f2bf(relv[((i & 31) << 6) + (i >> 5)]);
  __syncthreads();

  // acc += rv^T[d][r] * Pband[r][q]  (band + low), all unnormalized
  bf16x8 pb2 = *(const bf16x8*)((const u16*)Pband + (qloc << 5) + (g << 3));
#pragma unroll
  for (int dt = 0; dt < 4; ++dt) {
    bf16x8 av = *(const bf16x8*)(rvT + (((dt << 4) + c) << 5) + (g << 3));
    acc[dt] = MFMA16(av, pb2, acc[dt]);
  }

  const int b = bh >> 3, h = bh & 7;
  const int q = qbase + qloc;
  u16* xb = Xout + ((((size_t)b << 10) + q) << 9) + (h << 6);
#pragma unroll
  for (int dt = 0; dt < 4; ++dt) {
    int d0 = (dt << 4) + (g << 2);
    float v0 = (acc[dt][0] + hsum * rv32S[d0 + 0]) * inv;
    float v1 = (acc[dt][1] + hsum * rv32S[d0 + 1]) * inv;
    float v2 = (acc[dt][2] + hsum * rv32S[d0 + 2]) * inv;
    float v3 = (acc[dt][3] + hsum * rv32S[d0 + 3]) * inv;
    uint2 o;
    o.x = cvtpk(v0, v1);
    o.y = cvtpk(v2, v3);
    *(uint2*)(xb + d0) = o;
  }
#undef STAGE
}

// ---------------- launch ----------------
extern "C" void kernel_launch(void* const* d_in, const int* in_sizes, int n_in,
                              void* d_out, int out_size, void* d_ws, size_t ws_size,
                              hipStream_t stream) {
  (void)in_sizes; (void)n_in; (void)out_size; (void)ws_size;
  const float* query = (const float*)d_in[0];
  const float* key   = (const float*)d_in[1];
  const float* value = (const float*)d_in[2];
  const float* Wq = (const float*)d_in[3];
  const float* bq = (const float*)d_in[4];
  const float* Wk = (const float*)d_in[5];
  const float* bk = (const float*)d_in[6];
  const float* Wv = (const float*)d_in[7];
  const float* bv = (const float*)d_in[8];
  const float* Wo = (const float*)d_in[9];
  const float* bo = (const float*)d_in[10];
  const float* relk = (const float*)d_in[11];
  const float* relv = (const float*)d_in[12];

  char* ws = (char*)d_ws;
  u16*   Wqb   = (u16*)(ws + 25165824);
  u16*   Wkb   = (u16*)(ws + 25690112);
  u16*   Wvb   = (u16*)(ws + 26214400);
  u16*   Wob   = (u16*)(ws + 26738688);
  u16*   relkb = (u16*)(ws + 27262976);   // 33*64 bf16
  u16*   Qh    = (u16*)(ws + 27271168);
  u16*   Kh    = (u16*)(ws + 35659776);
  u16*   Vt    = (u16*)(ws + 52436992);
  u16*   Xout  = (u16*)(ws + 70262784);

  convW<<<1027, 256, 0, stream>>>(Wq, Wk, Wv, Wo, relk, Wqb, Wkb, Wvb, Wob, relkb);
  qkv_gemm<<<768, 256, 0, stream>>>(query, key, value, Wqb, Wkb, Wvb, bq, bk, bv, Qh, Kh, Vt);
  flash_kernel<<<512, 512, 0, stream>>>(Qh, Kh, Vt, relkb, relv, Xout);
  gemm_out<<<256, 256, 0, stream>>>(Xout, Wob, bo, (float*)d_out);
}

// Round 12
// 92.053 us; speedup vs baseline: 1.3887x; 1.1087x over previous
//
#include <hip/hip_runtime.h>

typedef unsigned short u16;
typedef float f32x4 __attribute__((ext_vector_type(4)));
typedef __bf16 bf16x8 __attribute__((ext_vector_type(8)));

#define MFMA16(a, b, c) __builtin_amdgcn_mfma_f32_16x16x32_bf16((a), (b), (c), 0, 0, 0)

#define B_ 8
#define H_ 8
#define S_ 1024

__device__ __forceinline__ u16 f2bf(float f) {
  unsigned u = __float_as_uint(f);
  return (u16)((u + 0x7fffu + ((u >> 16) & 1u)) >> 16);
}
// pack 2 f32 -> 2 bf16 in one instr (dst.lo = a, dst.hi = b)
__device__ __forceinline__ unsigned cvtpk(float a, float b) {
  unsigned r;
  asm("v_cvt_pk_bf16_f32 %0, %1, %2" : "=v"(r) : "v"(a), "v"(b));
  return r;
}
// async global->LDS, 16B per lane. LDS dest = wave-uniform base + lane*16.
__device__ __forceinline__ void gload16(const void* g, void* l) {
  __builtin_amdgcn_global_load_lds((__attribute__((address_space(1))) const void*)g,
                                   (__attribute__((address_space(3))) void*)l, 16, 0, 0);
}

// ---------------- weights + relk fp32->bf16 (3.15 MB only) ----------------
__global__ void __launch_bounds__(256) convW(const float* __restrict__ s0, const float* __restrict__ s1,
                                             const float* __restrict__ s2, const float* __restrict__ s3,
                                             const float* __restrict__ s4,
                                             u16* __restrict__ d0, u16* __restrict__ d1, u16* __restrict__ d2,
                                             u16* __restrict__ d3, u16* __restrict__ d4) {
  size_t i = ((size_t)blockIdx.x * 256 + threadIdx.x) << 2;
  if (i >= 1050688) return; // 4*262144 + 33*64
  const float* s; u16* d; size_t off;
  if (i < 262144)       { s = s0; d = d0; off = i; }
  else if (i < 524288)  { s = s1; d = d1; off = i - 262144; }
  else if (i < 786432)  { s = s2; d = d2; off = i - 524288; }
  else if (i < 1048576) { s = s3; d = d3; off = i - 786432; }
  else                  { s = s4; d = d4; off = i - 1048576; }
  float4 f = *(const float4*)(s + off);
  uint2 o;
  o.x = cvtpk(f.x, f.y);
  o.y = cvtpk(f.z, f.w);
  *(uint2*)(d + off) = o;
}

// ---------------- fused Q/K/V projection GEMM (768 blocks), A read directly from f32 ----------------
// seg 0: Q -> bf16 head-split [B,H,S,64]; seg 1: K same; seg 2: V -> transposed [B*H,64,S].
// A-tile staging: reg-stage f32 -> cvtpk -> ds_write_b128 into the same linear-swizzled slots.
// XCD-chunked block swizzle: the 4 bn-blocks sharing an A row-block land on the SAME XCD,
// so A is fetched from HBM once and re-read from that XCD's L2 (was: 4x HBM re-fetch).
__global__ void __launch_bounds__(256) qkv_gemm(const float* __restrict__ Aq, const float* __restrict__ Ak,
                                                const float* __restrict__ Av, const u16* __restrict__ Wqb,
                                                const u16* __restrict__ Wkb, const u16* __restrict__ Wvb,
                                                const float* __restrict__ bq, const float* __restrict__ bk,
                                                const float* __restrict__ bv, u16* __restrict__ Qh,
                                                u16* __restrict__ Kh, u16* __restrict__ Vt) {
  __shared__ u16 As[128 * 64];
  __shared__ u16 Bs[128 * 64];
  // 768 blocks, 8 XCDs, 96 per XCD (exact): XCD x gets logical work [96x, 96x+96)
  const int w = (blockIdx.x & 7) * 96 + (blockIdx.x >> 3);
  const int seg = w >> 8, bid = w & 255;
  const float* Af = seg == 0 ? Aq : (seg == 1 ? Ak : Av);
  const u16* W = seg == 0 ? Wqb : (seg == 1 ? Wkb : Wvb);
  const float* bias = seg == 0 ? bq : (seg == 1 ? bk : bv);
  const int tid = threadIdx.x, lane = tid & 63, wid = tid >> 6;
  const int c = lane & 15, g = lane >> 4;
  const int bm = bid >> 2, bn = bid & 3;
  const int m0 = bm << 7, n0 = bn << 7;
  const int wrow = (wid >> 1) << 6, wcol = (wid & 1) << 6;

  const f32x4 ZF = {0.f, 0.f, 0.f, 0.f};
  f32x4 acc[4][4];
#pragma unroll
  for (int i = 0; i < 4; ++i)
#pragma unroll
    for (int j = 0; j < 4; ++j) acc[i][j] = ZF;

  for (int kt = 0; kt < 512; kt += 64) {
    __syncthreads();
#pragma unroll
    for (int i = 0; i < 4; ++i) {
      int Lb = ((wid << 2) | i) << 10;
      int L = Lb + lane * 16;
      int row = L >> 7;                                 // 0..127
      int off = (L & 127) ^ ((row & 7) << 4);           // swizzled byte offset (bf16 domain)
      // A: load 8 f32 from true source position, convert, write to linear LDS slot
      const float* ap = Af + (((size_t)(m0 + row)) << 9) + kt + (off >> 1);
      float4 a0 = *(const float4*)ap;
      float4 a1 = *(const float4*)(ap + 4);
      uint4 aw;
      aw.x = cvtpk(a0.x, a0.y); aw.y = cvtpk(a0.z, a0.w);
      aw.z = cvtpk(a1.x, a1.y); aw.w = cvtpk(a1.z, a1.w);
      *(uint4*)((char*)As + L) = aw;
      // W: bf16, pre-swizzled async global->LDS
      gload16((const char*)W + ((((size_t)(n0 + row)) << 9) + kt) * 2 + off, (char*)Bs + Lb);
    }
    __syncthreads();
#pragma unroll
    for (int kk = 0; kk < 2; ++kk) {
      bf16x8 af[4], bfr[4];
#pragma unroll
      for (int rt = 0; rt < 4; ++rt) {
        int row = wrow + (rt << 4) + c;
        af[rt] = *(const bf16x8*)((const char*)As + row * 128 + (((kk << 6) | (g << 4)) ^ ((row & 7) << 4)));
      }
#pragma unroll
      for (int ct = 0; ct < 4; ++ct) {
        int row = wcol + (ct << 4) + c;
        bfr[ct] = *(const bf16x8*)((const char*)Bs + row * 128 + (((kk << 6) | (g << 4)) ^ ((row & 7) << 4)));
      }
#pragma unroll
      for (int rt = 0; rt < 4; ++rt)
#pragma unroll
        for (int ct = 0; ct < 4; ++ct) acc[rt][ct] = MFMA16(af[rt], bfr[ct], acc[rt][ct]);
    }
  }

#pragma unroll
  for (int rt = 0; rt < 4; ++rt)
#pragma unroll
    for (int ct = 0; ct < 4; ++ct) {
      int n = n0 + wcol + (ct << 4) + c;
      float bv2 = bias[n];
      if (seg == 2) {
        int b2 = m0 >> 10;
        int sbase = (m0 & 1023) + wrow + (rt << 4) + (g << 2);
        int h2 = n >> 6, d2 = n & 63;
        uint2 o;
        o.x = cvtpk(acc[rt][ct][0] + bv2, acc[rt][ct][1] + bv2);
        o.y = cvtpk(acc[rt][ct][2] + bv2, acc[rt][ct][3] + bv2);
        *(uint2*)(Vt + ((((size_t)((b2 << 3) + h2) << 6) + d2) << 10) + sbase) = o;
      } else {
        u16* out = seg == 0 ? Qh : Kh;
#pragma unroll
        for (int r = 0; r < 4; ++r) {
          int m = m0 + wrow + (rt << 4) + (g << 2) + r;
          int b = m >> 10, s = m & 1023, h = n >> 6, d = n & 63;
          out[(((((size_t)(b * H_ + h)) << 10) + s) << 6) + d] = f2bf(acc[rt][ct][r] + bv2);
        }
      }
    }
}

// ---------------- output GEMM: C fp32 [M][512] = A(bf16) @ W(bf16)^T + bias ----------------
__global__ void __launch_bounds__(256) gemm_out(const u16* __restrict__ A, const u16* __restrict__ W,
                                                const float* __restrict__ bias, float* __restrict__ out) {
  __shared__ u16 As[128 * 64];
  __shared__ u16 Bs[128 * 64];
  const int tid = threadIdx.x, lane = tid & 63, wid = tid >> 6;
  const int c = lane & 15, g = lane >> 4;
  const int bm = blockIdx.x >> 2, bn = blockIdx.x & 3;
  const int m0 = bm << 7, n0 = bn << 7;
  const int wrow = (wid >> 1) << 6, wcol = (wid & 1) << 6;

  const f32x4 ZF = {0.f, 0.f, 0.f, 0.f};
  f32x4 acc[4][4];
#pragma unroll
  for (int i = 0; i < 4; ++i)
#pragma unroll
    for (int j = 0; j < 4; ++j) acc[i][j] = ZF;

  for (int kt = 0; kt < 512; kt += 64) {
    __syncthreads();
#pragma unroll
    for (int i = 0; i < 4; ++i) {
      int Lb = ((wid << 2) | i) << 10;
      int L = Lb + lane * 16;
      int row = L >> 7;
      int off = (L & 127) ^ ((row & 7) << 4);
      gload16((const char*)A + ((((size_t)(m0 + row)) << 9) + kt) * 2 + off, (char*)As + Lb);
      gload16((const char*)W + ((((size_t)(n0 + row)) << 9) + kt) * 2 + off, (char*)Bs + Lb);
    }
    __syncthreads();
#pragma unroll
    for (int kk = 0; kk < 2; ++kk) {
      bf16x8 af[4], bfr[4];
#pragma unroll
      for (int rt = 0; rt < 4; ++rt) {
        int row = wrow + (rt << 4) + c;
        af[rt] = *(const bf16x8*)((const char*)As + row * 128 + (((kk << 6) | (g << 4)) ^ ((row & 7) << 4)));
      }
#pragma unroll
      for (int ct = 0; ct < 4; ++ct) {
        int row = wcol + (ct << 4) + c;
        bfr[ct] = *(const bf16x8*)((const char*)Bs + row * 128 + (((kk << 6) | (g << 4)) ^ ((row & 7) << 4)));
      }
#pragma unroll
      for (int rt = 0; rt < 4; ++rt)
#pragma unroll
        for (int ct = 0; ct < 4; ++ct) acc[rt][ct] = MFMA16(af[rt], bfr[ct], acc[rt][ct]);
    }
  }

#pragma unroll
  for (int rt = 0; rt < 4; ++rt)
#pragma unroll
    for (int ct = 0; ct < 4; ++ct) {
      int n = n0 + wcol + (ct << 4) + c;
      float bv = bias[n];
#pragma unroll
      for (int r = 0; r < 4; ++r) {
        int m = m0 + wrow + (rt << 4) + (g << 2) + r;
        out[(((size_t)m) << 9) + n] = acc[rt][ct][r] + bv;
      }
    }
}

// ---------------- flash attention: round-4 structure (8 waves, 128 q, fused qrel + rel-V) ----------------
// lane (c,g) of wave wid owns q = qbase + wid*16 + c everywhere.
__global__ void __launch_bounds__(512) flash_kernel(const u16* __restrict__ Qh, const u16* __restrict__ Kh,
                                                    const u16* __restrict__ Vt, const u16* __restrict__ relkb,
                                                    const float* __restrict__ relv, u16* __restrict__ Xout) {
  __shared__ u16 Ks[2][64 * 64];
  __shared__ u16 Vs[2][64 * 64];
  __shared__ u16 Ps[128 * 64];
  __shared__ float qrelS[128 * 34];   // exp2-domain bias table; overlaid by rvT in epilogue
  __shared__ u16 Pband[128 * 32];     // unnormalized bf16 band probs; slot 0 = low bucket
  __shared__ float rv32S[64];

  const int tid = threadIdx.x, lane = tid & 63, wid = tid >> 6;
  const int c = lane & 15, g = lane >> 4;
  // XCD swizzle: 8 chunks of 64 consecutive blocks
  const int swz = ((blockIdx.x & 7) << 6) | (blockIdx.x >> 3);
  const int bh = swz >> 3, qt = swz & 7;
  const int qbase = qt << 7;
  const size_t rowbase = ((size_t)bh) << 10;
  const int qloc = (wid << 4) + c;
  const float K1 = 0.51013619f;   // (1/sqrt(8)) * log2(e)
  const float C0 = 24.0f;

  // Q fragments (issue loads first)
  bf16x8 qa[2];
  {
    const u16* qptr = Qh + ((rowbase + qbase + qloc) << 6);
    qa[0] = *(const bf16x8*)(qptr + (g << 3));
    qa[1] = *(const bf16x8*)(qptr + 32 + (g << 3));
  }

#define STAGE(buf, kt_) do { \
    const int k64_ = (kt_) << 6; \
    int L_ = (wid << 10) + lane * 16; \
    int row_ = L_ >> 7; \
    int off_ = (L_ & 127) ^ ((row_ & 7) << 4); \
    gload16((const char*)Kh + ((rowbase + k64_ + row_) << 7) + off_, (char*)Ks[buf] + (wid << 10)); \
    gload16((const char*)Vt + ((((size_t)bh << 6) + row_) << 11) + (k64_ << 1) + off_, (char*)Vs[buf] + (wid << 10)); \
  } while (0)

  STAGE(0, 0);

  // zero Pband (8192B), load rv32
  ((uint4*)Pband)[tid] = uint4{0, 0, 0, 0};
  if (tid < 64) rv32S[tid] = relv[2048 + tid];

  // qrel in prologue: qrelS[q][r] = (Q[q,:].relk[r,:]) * K1 - C0, via 6 MFMAs per wave
  {
    const f32x4 ZF = {0.f, 0.f, 0.f, 0.f};
#pragma unroll
    for (int t = 0; t < 3; ++t) {
      int rr = t * 16 + c; if (rr > 32) rr = 32;
      f32x4 qr = ZF;
#pragma unroll
      for (int kk = 0; kk < 2; ++kk) {
        bf16x8 ar = *(const bf16x8*)(relkb + (rr << 6) + (kk << 5) + (g << 3));
        qr = MFMA16(ar, qa[kk], qr);
      }
#pragma unroll
      for (int j = 0; j < 4; ++j) {
        int r = t * 16 + (g << 2) + j;
        if (r < 33) qrelS[qloc * 34 + r] = qr[j] * K1 - C0;
      }
    }
  }
  __syncthreads();   // covers STAGE(0), Pband init, qrelS, rv32S

  const float bias_lo = qrelS[qloc * 34 + 0];
  const float bias_hi = qrelS[qloc * 34 + 32];

  // hoisted loop-invariant LDS byte offsets
  int koff[4][2], voff[4][2], poffw[4];
#pragma unroll
  for (int t = 0; t < 4; ++t) {
#pragma unroll
    for (int kk = 0; kk < 2; ++kk)
      koff[t][kk] = ((t << 4) + c) * 128 + ((((kk << 6) | (g << 4))) ^ ((c & 7) << 4));
#pragma unroll
    for (int h2 = 0; h2 < 2; ++h2)
      voff[t][h2] = ((t << 4) + c) * 128 + ((((h2 << 6) | (g << 4))) ^ ((c & 7) << 4));
    poffw[t] = qloc * 128 + (((t << 5) | (g << 3)) ^ ((c & 7) << 4));
  }
  const int pr0 = qloc * 128 + ((g << 4) ^ ((c & 7) << 4));
  const int pr1 = pr0 ^ 64;

  const f32x4 ZF = {0.f, 0.f, 0.f, 0.f};
  f32x4 acc[4] = {ZF, ZF, ZF, ZF};
  float lsum = 0.f, lowsum = 0.f, psum = 0.f;

  for (int kt = 0; kt < 16; ++kt) {
    const int cur = kt & 1;
    if (kt < 15) STAGE(cur ^ 1, kt + 1);   // prefetch into other buffer

    // QK^T swapped: sa[t][j] = S[k = kt*64 + t*16 + g*4 + j][q = own]
    f32x4 sa[4];
#pragma unroll
    for (int t = 0; t < 4; ++t) {
      sa[t] = ZF;
#pragma unroll
      for (int kk = 0; kk < 2; ++kk) {
        bf16x8 bk = *(const bf16x8*)((const char*)Ks + (cur << 13) + koff[t][kk]);
        sa[t] = MFMA16(bk, qa[kk], sa[t]);
      }
    }

    const int D0 = (kt << 6) - qbase;
    float p[4][4];
    if (D0 >= 192) {            // all dlt >= 17: high bucket
      float s = 0.f;
#pragma unroll
      for (int t = 0; t < 4; ++t)
#pragma unroll
        for (int j = 0; j < 4; ++j) {
          float pe = __builtin_amdgcn_exp2f(fmaf(sa[t][j], K1, bias_hi));
          p[t][j] = pe; s += pe;
        }
      lsum += s;
    } else if (D0 <= -128) {    // all dlt <= -17: low bucket
      float s = 0.f;
#pragma unroll
      for (int t = 0; t < 4; ++t)
#pragma unroll
        for (int j = 0; j < 4; ++j) {
          float pe = __builtin_amdgcn_exp2f(fmaf(sa[t][j], K1, bias_lo));
          p[t][j] = pe; s += pe;
        }
      lsum += s; lowsum += s;
    } else {                    // boundary tiles (4 of 16)
#pragma unroll
      for (int t = 0; t < 4; ++t)
#pragma unroll
        for (int j = 0; j < 4; ++j) {
          int dlt = D0 + (t << 4) + (g << 2) + j - qloc;
          int idx = dlt < -16 ? 0 : (dlt > 16 ? 32 : dlt + 16);
          float pe = __builtin_amdgcn_exp2f(fmaf(sa[t][j], K1, qrelS[qloc * 34 + idx]));
          p[t][j] = pe;
          lsum += pe;
          if (dlt <= -16) lowsum += pe;
          else if (dlt < 16) { psum += pe; Pband[(qloc << 5) + dlt + 16] = f2bf(pe); }
        }
    }

    // P -> LDS (own row), then PV swapped: acc[dt][j] = O[d = dt*16+g*4+j][q = own]
#pragma unroll
    for (int t = 0; t < 4; ++t) {
      uint2 pk;
      pk.x = cvtpk(p[t][0], p[t][1]);
      pk.y = cvtpk(p[t][2], p[t][3]);
      *(uint2*)((char*)Ps + poffw[t]) = pk;
    }
    bf16x8 pb0 = *(const bf16x8*)((const char*)Ps + pr0);
    bf16x8 pb1 = *(const bf16x8*)((const char*)Ps + pr1);
#pragma unroll
    for (int dt = 0; dt < 4; ++dt) {
      bf16x8 av0 = *(const bf16x8*)((const char*)Vs + (cur << 13) + voff[dt][0]);
      bf16x8 av1 = *(const bf16x8*)((const char*)Vs + (cur << 13) + voff[dt][1]);
      acc[dt] = MFMA16(av0, pb0, acc[dt]);
      acc[dt] = MFMA16(av1, pb1, acc[dt]);
    }
    __syncthreads();   // drains prefetch + protects dbuf swap
  }

  // ---- epilogue ----
  lsum += __shfl_xor(lsum, 16);   lsum += __shfl_xor(lsum, 32);
  lowsum += __shfl_xor(lowsum, 16); lowsum += __shfl_xor(lowsum, 32);
  psum += __shfl_xor(psum, 16);   psum += __shfl_xor(psum, 32);
  const float inv = 1.f / lsum;
  const float hsum = lsum - lowsum - psum;   // unnormalized high-bucket mass

  if (g == 0) Pband[qloc << 5] = f2bf(lowsum);   // low bucket slot (unnormalized)

  // overlay rv^T (bf16 [d][r=0..31]) into dead qrelS
  u16* rvT = (u16*)qrelS;
  for (int i = tid; i < 4096; i += 512) rvT[i] = f2bf(relv[((i & 31) << 6) + (i >> 5)]);
  __syncthreads();

  // acc += rv^T[d][r] * Pband[r][q]  (band + low), all unnormalized
  bf16x8 pb2 = *(const bf16x8*)((const u16*)Pband + (qloc << 5) + (g << 3));
#pragma unroll
  for (int dt = 0; dt < 4; ++dt) {
    bf16x8 av = *(const bf16x8*)(rvT + (((dt << 4) + c) << 5) + (g << 3));
    acc[dt] = MFMA16(av, pb2, acc[dt]);
  }

  const int b = bh >> 3, h = bh & 7;
  const int q = qbase + qloc;
  u16* xb = Xout + ((((size_t)b << 10) + q) << 9) + (h << 6);
#pragma unroll
  for (int dt = 0; dt < 4; ++dt) {
    int d0 = (dt << 4) + (g << 2);
    float v0 = (acc[dt][0] + hsum * rv32S[d0 + 0]) * inv;
    float v1 = (acc[dt][1] + hsum * rv32S[d0 + 1]) * inv;
    float v2 = (acc[dt][2] + hsum * rv32S[d0 + 2]) * inv;
    float v3 = (acc[dt][3] + hsum * rv32S[d0 + 3]) * inv;
    uint2 o;
    o.x = cvtpk(v0, v1);
    o.y = cvtpk(v2, v3);
    *(uint2*)(xb + d0) = o;
  }
#undef STAGE
}

// ---------------- launch ----------------
extern "C" void kernel_launch(void* const* d_in, const int* in_sizes, int n_in,
                              void* d_out, int out_size, void* d_ws, size_t ws_size,
                              hipStream_t stream) {
  (void)in_sizes; (void)n_in; (void)out_size; (void)ws_size;
  const float* query = (const float*)d_in[0];
  const float* key   = (const float*)d_in[1];
  const float* value = (const float*)d_in[2];
  const float* Wq = (const float*)d_in[3];
  const float* bq = (const float*)d_in[4];
  const float* Wk = (const float*)d_in[5];
  const float* bk = (const float*)d_in[6];
  const float* Wv = (const float*)d_in[7];
  const float* bv = (const float*)d_in[8];
  const float* Wo = (const float*)d_in[9];
  const float* bo = (const float*)d_in[10];
  const float* relk = (const float*)d_in[11];
  const float* relv = (const float*)d_in[12];

  char* ws = (char*)d_ws;
  u16*   Wqb   = (u16*)(ws + 25165824);
  u16*   Wkb   = (u16*)(ws + 25690112);
  u16*   Wvb   = (u16*)(ws + 26214400);
  u16*   Wob   = (u16*)(ws + 26738688);
  u16*   relkb = (u16*)(ws + 27262976);   // 33*64 bf16
  u16*   Qh    = (u16*)(ws + 27271168);
  u16*   Kh    = (u16*)(ws + 35659776);
  u16*   Vt    = (u16*)(ws + 52436992);
  u16*   Xout  = (u16*)(ws + 70262784);

  convW<<<1027, 256, 0, stream>>>(Wq, Wk, Wv, Wo, relk, Wqb, Wkb, Wvb, Wob, relkb);
  qkv_gemm<<<768, 256, 0, stream>>>(query, key, value, Wqb, Wkb, Wvb, bq, bk, bv, Qh, Kh, Vt);
  flash_kernel<<<512, 512, 0, stream>>>(Qh, Kh, Vt, relkb, relv, Xout);
  gemm_out<<<256, 256, 0, stream>>>(Xout, Wob, bo, (float*)d_out);
}

// Round 13
// 89.374 us; speedup vs baseline: 1.4304x; 1.0300x over previous
//
#include <hip/hip_runtime.h>

typedef unsigned short u16;
typedef float f32x4 __attribute__((ext_vector_type(4)));
typedef __bf16 bf16x8 __attribute__((ext_vector_type(8)));

#define MFMA16(a, b, c) __builtin_amdgcn_mfma_f32_16x16x32_bf16((a), (b), (c), 0, 0, 0)

#define B_ 8
#define H_ 8
#define S_ 1024

__device__ __forceinline__ u16 f2bf(float f) {
  unsigned u = __float_as_uint(f);
  return (u16)((u + 0x7fffu + ((u >> 16) & 1u)) >> 16);
}
// pack 2 f32 -> 2 bf16 in one instr (dst.lo = a, dst.hi = b)
__device__ __forceinline__ unsigned cvtpk(float a, float b) {
  unsigned r;
  asm("v_cvt_pk_bf16_f32 %0, %1, %2" : "=v"(r) : "v"(a), "v"(b));
  return r;
}
// async global->LDS, 16B per lane. LDS dest = wave-uniform base + lane*16.
__device__ __forceinline__ void gload16(const void* g, void* l) {
  __builtin_amdgcn_global_load_lds((__attribute__((address_space(1))) const void*)g,
                                   (__attribute__((address_space(3))) void*)l, 16, 0, 0);
}

// ---------------- weights + relk fp32->bf16 (3.15 MB only) ----------------
__global__ void __launch_bounds__(256) convW(const float* __restrict__ s0, const float* __restrict__ s1,
                                             const float* __restrict__ s2, const float* __restrict__ s3,
                                             const float* __restrict__ s4,
                                             u16* __restrict__ d0, u16* __restrict__ d1, u16* __restrict__ d2,
                                             u16* __restrict__ d3, u16* __restrict__ d4) {
  size_t i = ((size_t)blockIdx.x * 256 + threadIdx.x) << 2;
  if (i >= 1050688) return; // 4*262144 + 33*64
  const float* s; u16* d; size_t off;
  if (i < 262144)       { s = s0; d = d0; off = i; }
  else if (i < 524288)  { s = s1; d = d1; off = i - 262144; }
  else if (i < 786432)  { s = s2; d = d2; off = i - 524288; }
  else if (i < 1048576) { s = s3; d = d3; off = i - 786432; }
  else                  { s = s4; d = d4; off = i - 1048576; }
  float4 f = *(const float4*)(s + off);
  uint2 o;
  o.x = cvtpk(f.x, f.y);
  o.y = cvtpk(f.z, f.w);
  *(uint2*)(d + off) = o;
}

// ---------------- fused Q/K/V projection GEMM (768 blocks), A staged as f32 via async DMA ----------------
// seg 0: Q -> bf16 head-split [B,H,S,64]; seg 1: K same; seg 2: V -> transposed [B*H,64,S].
// A-tile: gload16 f32 into 32KB LDS (source pre-swizzled at 16B granule within 256B rows; LDS linear).
// Fragment read = 2x ds_read_b128 (f32) + 4x cvt_pk (VALU overlaps MFMA). No register staging chain.
// XCD-chunked block swizzle keeps the 4 bn-blocks of one A row-block on the same XCD's L2.
__global__ void __launch_bounds__(256) qkv_gemm(const float* __restrict__ Aq, const float* __restrict__ Ak,
                                                const float* __restrict__ Av, const u16* __restrict__ Wqb,
                                                const u16* __restrict__ Wkb, const u16* __restrict__ Wvb,
                                                const float* __restrict__ bq, const float* __restrict__ bk,
                                                const float* __restrict__ bv, u16* __restrict__ Qh,
                                                u16* __restrict__ Kh, u16* __restrict__ Vt) {
  __shared__ float Asf[128 * 64];   // 32 KB f32 A tile
  __shared__ u16 Bs[128 * 64];      // 16 KB bf16 W tile
  // 768 blocks, 8 XCDs, 96 per XCD (exact): XCD x gets logical work [96x, 96x+96)
  const int w = (blockIdx.x & 7) * 96 + (blockIdx.x >> 3);
  const int seg = w >> 8, bid = w & 255;
  const float* Af = seg == 0 ? Aq : (seg == 1 ? Ak : Av);
  const u16* W = seg == 0 ? Wqb : (seg == 1 ? Wkb : Wvb);
  const float* bias = seg == 0 ? bq : (seg == 1 ? bk : bv);
  const int tid = threadIdx.x, lane = tid & 63, wid = tid >> 6;
  const int c = lane & 15, g = lane >> 4;
  const int bm = bid >> 2, bn = bid & 3;
  const int m0 = bm << 7, n0 = bn << 7;
  const int wrow = (wid >> 1) << 6, wcol = (wid & 1) << 6;

  const f32x4 ZF = {0.f, 0.f, 0.f, 0.f};
  f32x4 acc[4][4];
#pragma unroll
  for (int i = 0; i < 4; ++i)
#pragma unroll
    for (int j = 0; j < 4; ++j) acc[i][j] = ZF;

  for (int kt = 0; kt < 512; kt += 64) {
    __syncthreads();
    // W: bf16, pre-swizzled async global->LDS (4 calls/wave)
#pragma unroll
    for (int i = 0; i < 4; ++i) {
      int Lb = ((wid << 2) | i) << 10;
      int L = Lb + lane * 16;
      int row = L >> 7;                                 // 0..127
      int off = (L & 127) ^ ((row & 7) << 4);           // pre-swizzled source (bf16 domain)
      gload16((const char*)W + ((((size_t)(n0 + row)) << 9) + kt) * 2 + off, (char*)Bs + Lb);
    }
    // A: f32, pre-swizzled at 16B granule within 256B rows, async global->LDS (8 calls/wave)
#pragma unroll
    for (int j = 0; j < 8; ++j) {
      int sb = ((wid << 3) | j) << 6;       // wave-uniform slot base (16B units)
      int s = sb + lane;
      int row = s >> 4;                     // 0..127 (16 slots of 16B per 256B row)
      int colb = (s & 15) << 4;             // byte col within row
      int colb_s = colb ^ ((row & 7) << 4); // pre-swizzled source col
      gload16((const char*)Af + (((size_t)(m0 + row)) << 11) + (kt << 2) + colb_s,
              (char*)Asf + (sb << 4));
    }
    __syncthreads();
#pragma unroll
    for (int kk = 0; kk < 2; ++kk) {
      bf16x8 af[4], bfr[4];
#pragma unroll
      for (int rt = 0; rt < 4; ++rt) {
        int row = wrow + (rt << 4) + c;
        int swz = (row & 7) << 4;
        const char* pA = (const char*)Asf + row * 256;
        int bb = (kk << 7) + (g << 5);      // byte col base (32B aligned)
        float4 f0 = *(const float4*)(pA + (bb ^ swz));
        float4 f1 = *(const float4*)(pA + ((bb + 16) ^ swz));
        uint4 aw;
        aw.x = cvtpk(f0.x, f0.y); aw.y = cvtpk(f0.z, f0.w);
        aw.z = cvtpk(f1.x, f1.y); aw.w = cvtpk(f1.z, f1.w);
        af[rt] = __builtin_bit_cast(bf16x8, aw);
      }
#pragma unroll
      for (int ct = 0; ct < 4; ++ct) {
        int row = wcol + (ct << 4) + c;
        bfr[ct] = *(const bf16x8*)((const char*)Bs + row * 128 + (((kk << 6) | (g << 4)) ^ ((row & 7) << 4)));
      }
#pragma unroll
      for (int rt = 0; rt < 4; ++rt)
#pragma unroll
        for (int ct = 0; ct < 4; ++ct) acc[rt][ct] = MFMA16(af[rt], bfr[ct], acc[rt][ct]);
    }
  }

#pragma unroll
  for (int rt = 0; rt < 4; ++rt)
#pragma unroll
    for (int ct = 0; ct < 4; ++ct) {
      int n = n0 + wcol + (ct << 4) + c;
      float bv2 = bias[n];
      if (seg == 2) {
        int b2 = m0 >> 10;
        int sbase = (m0 & 1023) + wrow + (rt << 4) + (g << 2);
        int h2 = n >> 6, d2 = n & 63;
        uint2 o;
        o.x = cvtpk(acc[rt][ct][0] + bv2, acc[rt][ct][1] + bv2);
        o.y = cvtpk(acc[rt][ct][2] + bv2, acc[rt][ct][3] + bv2);
        *(uint2*)(Vt + ((((size_t)((b2 << 3) + h2) << 6) + d2) << 10) + sbase) = o;
      } else {
        u16* out = seg == 0 ? Qh : Kh;
#pragma unroll
        for (int r = 0; r < 4; ++r) {
          int m = m0 + wrow + (rt << 4) + (g << 2) + r;
          int b = m >> 10, s = m & 1023, h = n >> 6, d = n & 63;
          out[(((((size_t)(b * H_ + h)) << 10) + s) << 6) + d] = f2bf(acc[rt][ct][r] + bv2);
        }
      }
    }
}

// ---------------- output GEMM: C fp32 [M][512] = A(bf16) @ W(bf16)^T + bias ----------------
__global__ void __launch_bounds__(256) gemm_out(const u16* __restrict__ A, const u16* __restrict__ W,
                                                const float* __restrict__ bias, float* __restrict__ out) {
  __shared__ u16 As[128 * 64];
  __shared__ u16 Bs[128 * 64];
  // XCD swizzle: 256 blocks, 32 per XCD (exact)
  const int wb = (blockIdx.x & 7) * 32 + (blockIdx.x >> 3);
  const int tid = threadIdx.x, lane = tid & 63, wid = tid >> 6;
  const int c = lane & 15, g = lane >> 4;
  const int bm = wb >> 2, bn = wb & 3;
  const int m0 = bm << 7, n0 = bn << 7;
  const int wrow = (wid >> 1) << 6, wcol = (wid & 1) << 6;

  const f32x4 ZF = {0.f, 0.f, 0.f, 0.f};
  f32x4 acc[4][4];
#pragma unroll
  for (int i = 0; i < 4; ++i)
#pragma unroll
    for (int j = 0; j < 4; ++j) acc[i][j] = ZF;

  for (int kt = 0; kt < 512; kt += 64) {
    __syncthreads();
#pragma unroll
    for (int i = 0; i < 4; ++i) {
      int Lb = ((wid << 2) | i) << 10;
      int L = Lb + lane * 16;
      int row = L >> 7;
      int off = (L & 127) ^ ((row & 7) << 4);
      gload16((const char*)A + ((((size_t)(m0 + row)) << 9) + kt) * 2 + off, (char*)As + Lb);
      gload16((const char*)W + ((((size_t)(n0 + row)) << 9) + kt) * 2 + off, (char*)Bs + Lb);
    }
    __syncthreads();
#pragma unroll
    for (int kk = 0; kk < 2; ++kk) {
      bf16x8 af[4], bfr[4];
#pragma unroll
      for (int rt = 0; rt < 4; ++rt) {
        int row = wrow + (rt << 4) + c;
        af[rt] = *(const bf16x8*)((const char*)As + row * 128 + (((kk << 6) | (g << 4)) ^ ((row & 7) << 4)));
      }
#pragma unroll
      for (int ct = 0; ct < 4; ++ct) {
        int row = wcol + (ct << 4) + c;
        bfr[ct] = *(const bf16x8*)((const char*)Bs + row * 128 + (((kk << 6) | (g << 4)) ^ ((row & 7) << 4)));
      }
#pragma unroll
      for (int rt = 0; rt < 4; ++rt)
#pragma unroll
        for (int ct = 0; ct < 4; ++ct) acc[rt][ct] = MFMA16(af[rt], bfr[ct], acc[rt][ct]);
    }
  }

#pragma unroll
  for (int rt = 0; rt < 4; ++rt)
#pragma unroll
    for (int ct = 0; ct < 4; ++ct) {
      int n = n0 + wcol + (ct << 4) + c;
      float bv = bias[n];
#pragma unroll
      for (int r = 0; r < 4; ++r) {
        int m = m0 + wrow + (rt << 4) + (g << 2) + r;
        out[(((size_t)m) << 9) + n] = acc[rt][ct][r] + bv;
      }
    }
}

// ---------------- flash attention: round-4 structure (8 waves, 128 q, fused qrel + rel-V) ----------------
// lane (c,g) of wave wid owns q = qbase + wid*16 + c everywhere.
__global__ void __launch_bounds__(512) flash_kernel(const u16* __restrict__ Qh, const u16* __restrict__ Kh,
                                                    const u16* __restrict__ Vt, const u16* __restrict__ relkb,
                                                    const float* __restrict__ relv, u16* __restrict__ Xout) {
  __shared__ u16 Ks[2][64 * 64];
  __shared__ u16 Vs[2][64 * 64];
  __shared__ u16 Ps[128 * 64];
  __shared__ float qrelS[128 * 34];   // exp2-domain bias table; overlaid by rvT in epilogue
  __shared__ u16 Pband[128 * 32];     // unnormalized bf16 band probs; slot 0 = low bucket
  __shared__ float rv32S[64];

  const int tid = threadIdx.x, lane = tid & 63, wid = tid >> 6;
  const int c = lane & 15, g = lane >> 4;
  // XCD swizzle: 8 chunks of 64 consecutive blocks
  const int swz = ((blockIdx.x & 7) << 6) | (blockIdx.x >> 3);
  const int bh = swz >> 3, qt = swz & 7;
  const int qbase = qt << 7;
  const size_t rowbase = ((size_t)bh) << 10;
  const int qloc = (wid << 4) + c;
  const float K1 = 0.51013619f;   // (1/sqrt(8)) * log2(e)
  const float C0 = 24.0f;

  // Q fragments (issue loads first)
  bf16x8 qa[2];
  {
    const u16* qptr = Qh + ((rowbase + qbase + qloc) << 6);
    qa[0] = *(const bf16x8*)(qptr + (g << 3));
    qa[1] = *(const bf16x8*)(qptr + 32 + (g << 3));
  }

#define STAGE(buf, kt_) do { \
    const int k64_ = (kt_) << 6; \
    int L_ = (wid << 10) + lane * 16; \
    int row_ = L_ >> 7; \
    int off_ = (L_ & 127) ^ ((row_ & 7) << 4); \
    gload16((const char*)Kh + ((rowbase + k64_ + row_) << 7) + off_, (char*)Ks[buf] + (wid << 10)); \
    gload16((const char*)Vt + ((((size_t)bh << 6) + row_) << 11) + (k64_ << 1) + off_, (char*)Vs[buf] + (wid << 10)); \
  } while (0)

  STAGE(0, 0);

  // zero Pband (8192B), load rv32
  ((uint4*)Pband)[tid] = uint4{0, 0, 0, 0};
  if (tid < 64) rv32S[tid] = relv[2048 + tid];

  // qrel in prologue: qrelS[q][r] = (Q[q,:].relk[r,:]) * K1 - C0, via 6 MFMAs per wave
  {
    const f32x4 ZF = {0.f, 0.f, 0.f, 0.f};
#pragma unroll
    for (int t = 0; t < 3; ++t) {
      int rr = t * 16 + c; if (rr > 32) rr = 32;
      f32x4 qr = ZF;
#pragma unroll
      for (int kk = 0; kk < 2; ++kk) {
        bf16x8 ar = *(const bf16x8*)(relkb + (rr << 6) + (kk << 5) + (g << 3));
        qr = MFMA16(ar, qa[kk], qr);
      }
#pragma unroll
      for (int j = 0; j < 4; ++j) {
        int r = t * 16 + (g << 2) + j;
        if (r < 33) qrelS[qloc * 34 + r] = qr[j] * K1 - C0;
      }
    }
  }
  __syncthreads();   // covers STAGE(0), Pband init, qrelS, rv32S

  const float bias_lo = qrelS[qloc * 34 + 0];
  const float bias_hi = qrelS[qloc * 34 + 32];

  // hoisted loop-invariant LDS byte offsets
  int koff[4][2], voff[4][2], poffw[4];
#pragma unroll
  for (int t = 0; t < 4; ++t) {
#pragma unroll
    for (int kk = 0; kk < 2; ++kk)
      koff[t][kk] = ((t << 4) + c) * 128 + ((((kk << 6) | (g << 4))) ^ ((c & 7) << 4));
#pragma unroll
    for (int h2 = 0; h2 < 2; ++h2)
      voff[t][h2] = ((t << 4) + c) * 128 + ((((h2 << 6) | (g << 4))) ^ ((c & 7) << 4));
    poffw[t] = qloc * 128 + (((t << 5) | (g << 3)) ^ ((c & 7) << 4));
  }
  const int pr0 = qloc * 128 + ((g << 4) ^ ((c & 7) << 4));
  const int pr1 = pr0 ^ 64;

  const f32x4 ZF = {0.f, 0.f, 0.f, 0.f};
  f32x4 acc[4] = {ZF, ZF, ZF, ZF};
  float lsum = 0.f, lowsum = 0.f, psum = 0.f;

  for (int kt = 0; kt < 16; ++kt) {
    const int cur = kt & 1;
    if (kt < 15) STAGE(cur ^ 1, kt + 1);   // prefetch into other buffer

    // QK^T swapped: sa[t][j] = S[k = kt*64 + t*16 + g*4 + j][q = own]
    f32x4 sa[4];
#pragma unroll
    for (int t = 0; t < 4; ++t) {
      sa[t] = ZF;
#pragma unroll
      for (int kk = 0; kk < 2; ++kk) {
        bf16x8 bk = *(const bf16x8*)((const char*)Ks + (cur << 13) + koff[t][kk]);
        sa[t] = MFMA16(bk, qa[kk], sa[t]);
      }
    }

    const int D0 = (kt << 6) - qbase;
    float p[4][4];
    if (D0 >= 192) {            // all dlt >= 17: high bucket
      float s = 0.f;
#pragma unroll
      for (int t = 0; t < 4; ++t)
#pragma unroll
        for (int j = 0; j < 4; ++j) {
          float pe = __builtin_amdgcn_exp2f(fmaf(sa[t][j], K1, bias_hi));
          p[t][j] = pe; s += pe;
        }
      lsum += s;
    } else if (D0 <= -128) {    // all dlt <= -17: low bucket
      float s = 0.f;
#pragma unroll
      for (int t = 0; t < 4; ++t)
#pragma unroll
        for (int j = 0; j < 4; ++j) {
          float pe = __builtin_amdgcn_exp2f(fmaf(sa[t][j], K1, bias_lo));
          p[t][j] = pe; s += pe;
        }
      lsum += s; lowsum += s;
    } else {                    // boundary tiles (4 of 16)
#pragma unroll
      for (int t = 0; t < 4; ++t)
#pragma unroll
        for (int j = 0; j < 4; ++j) {
          int dlt = D0 + (t << 4) + (g << 2) + j - qloc;
          int idx = dlt < -16 ? 0 : (dlt > 16 ? 32 : dlt + 16);
          float pe = __builtin_amdgcn_exp2f(fmaf(sa[t][j], K1, qrelS[qloc * 34 + idx]));
          p[t][j] = pe;
          lsum += pe;
          if (dlt <= -16) lowsum += pe;
          else if (dlt < 16) { psum += pe; Pband[(qloc << 5) + dlt + 16] = f2bf(pe); }
        }
    }

    // P -> LDS (own row), then PV swapped: acc[dt][j] = O[d = dt*16+g*4+j][q = own]
#pragma unroll
    for (int t = 0; t < 4; ++t) {
      uint2 pk;
      pk.x = cvtpk(p[t][0], p[t][1]);
      pk.y = cvtpk(p[t][2], p[t][3]);
      *(uint2*)((char*)Ps + poffw[t]) = pk;
    }
    bf16x8 pb0 = *(const bf16x8*)((const char*)Ps + pr0);
    bf16x8 pb1 = *(const bf16x8*)((const char*)Ps + pr1);
#pragma unroll
    for (int dt = 0; dt < 4; ++dt) {
      bf16x8 av0 = *(const bf16x8*)((const char*)Vs + (cur << 13) + voff[dt][0]);
      bf16x8 av1 = *(const bf16x8*)((const char*)Vs + (cur << 13) + voff[dt][1]);
      acc[dt] = MFMA16(av0, pb0, acc[dt]);
      acc[dt] = MFMA16(av1, pb1, acc[dt]);
    }
    __syncthreads();   // drains prefetch + protects dbuf swap
  }

  // ---- epilogue ----
  lsum += __shfl_xor(lsum, 16);   lsum += __shfl_xor(lsum, 32);
  lowsum += __shfl_xor(lowsum, 16); lowsum += __shfl_xor(lowsum, 32);
  psum += __shfl_xor(psum, 16);   psum += __shfl_xor(psum, 32);
  const float inv = 1.f / lsum;
  const float hsum = lsum - lowsum - psum;   // unnormalized high-bucket mass

  if (g == 0) Pband[qloc << 5] = f2bf(lowsum);   // low bucket slot (unnormalized)

  // overlay rv^T (bf16 [d][r=0..31]) into dead qrelS
  u16* rvT = (u16*)qrelS;
  for (int i = tid; i < 4096; i += 512) rvT[i] = f2bf(relv[((i & 31) << 6) + (i >> 5)]);
  __syncthreads();

  // acc += rv^T[d][r] * Pband[r][q]  (band + low), all unnormalized
  bf16x8 pb2 = *(const bf16x8*)((const u16*)Pband + (qloc << 5) + (g << 3));
#pragma unroll
  for (int dt = 0; dt < 4; ++dt) {
    bf16x8 av = *(const bf16x8*)(rvT + (((dt << 4) + c) << 5) + (g << 3));
    acc[dt] = MFMA16(av, pb2, acc[dt]);
  }

  const int b = bh >> 3, h = bh & 7;
  const int q = qbase + qloc;
  u16* xb = Xout + ((((size_t)b << 10) + q) << 9) + (h << 6);
#pragma unroll
  for (int dt = 0; dt < 4; ++dt) {
    int d0 = (dt << 4) + (g << 2);
    float v0 = (acc[dt][0] + hsum * rv32S[d0 + 0]) * inv;
    float v1 = (acc[dt][1] + hsum * rv32S[d0 + 1]) * inv;
    float v2 = (acc[dt][2] + hsum * rv32S[d0 + 2]) * inv;
    float v3 = (acc[dt][3] + hsum * rv32S[d0 + 3]) * inv;
    uint2 o;
    o.x = cvtpk(v0, v1);
    o.y = cvtpk(v2, v3);
    *(uint2*)(xb + d0) = o;
  }
#undef STAGE
}

// ---------------- launch ----------------
extern "C" void kernel_launch(void* const* d_in, const int* in_sizes, int n_in,
                              void* d_out, int out_size, void* d_ws, size_t ws_size,
                              hipStream_t stream) {
  (void)in_sizes; (void)n_in; (void)out_size; (void)ws_size;
  const float* query = (const float*)d_in[0];
  const float* key   = (const float*)d_in[1];
  const float* value = (const float*)d_in[2];
  const float* Wq = (const float*)d_in[3];
  const float* bq = (const float*)d_in[4];
  const float* Wk = (const float*)d_in[5];
  const float* bk = (const float*)d_in[6];
  const float* Wv = (const float*)d_in[7];
  const float* bv = (const float*)d_in[8];
  const float* Wo = (const float*)d_in[9];
  const float* bo = (const float*)d_in[10];
  const float* relk = (const float*)d_in[11];
  const float* relv = (const float*)d_in[12];

  char* ws = (char*)d_ws;
  u16*   Wqb   = (u16*)(ws + 25165824);
  u16*   Wkb   = (u16*)(ws + 25690112);
  u16*   Wvb   = (u16*)(ws + 26214400);
  u16*   Wob   = (u16*)(ws + 26738688);
  u16*   relkb = (u16*)(ws + 27262976);   // 33*64 bf16
  u16*   Qh    = (u16*)(ws + 27271168);
  u16*   Kh    = (u16*)(ws + 35659776);
  u16*   Vt    = (u16*)(ws + 52436992);
  u16*   Xout  = (u16*)(ws + 70262784);

  convW<<<1027, 256, 0, stream>>>(Wq, Wk, Wv, Wo, relk, Wqb, Wkb, Wvb, Wob, relkb);
  qkv_gemm<<<768, 256, 0, stream>>>(query, key, value, Wqb, Wkb, Wvb, bq, bk, bv, Qh, Kh, Vt);
  flash_kernel<<<512, 512, 0, stream>>>(Qh, Kh, Vt, relkb, relv, Xout);
  gemm_out<<<256, 256, 0, stream>>>(Xout, Wob, bo, (float*)d_out);
}

// Round 14
// 86.343 us; speedup vs baseline: 1.4806x; 1.0351x over previous
//
#include <hip/hip_runtime.h>

typedef unsigned short u16;
typedef float f32x4 __attribute__((ext_vector_type(4)));
typedef __bf16 bf16x8 __attribute__((ext_vector_type(8)));

#define MFMA16(a, b, c) __builtin_amdgcn_mfma_f32_16x16x32_bf16((a), (b), (c), 0, 0, 0)

#define B_ 8
#define H_ 8
#define S_ 1024

__device__ __forceinline__ u16 f2bf(float f) {
  unsigned u = __float_as_uint(f);
  return (u16)((u + 0x7fffu + ((u >> 16) & 1u)) >> 16);
}
// pack 2 f32 -> 2 bf16 in one instr (dst.lo = a, dst.hi = b)
__device__ __forceinline__ unsigned cvtpk(float a, float b) {
  unsigned r;
  asm("v_cvt_pk_bf16_f32 %0, %1, %2" : "=v"(r) : "v"(a), "v"(b));
  return r;
}
// async global->LDS, 16B per lane. LDS dest = wave-uniform base + lane*16.
__device__ __forceinline__ void gload16(const void* g, void* l) {
  __builtin_amdgcn_global_load_lds((__attribute__((address_space(1))) const void*)g,
                                   (__attribute__((address_space(3))) void*)l, 16, 0, 0);
}

// ---------------- weights + relk fp32->bf16 (3.15 MB only) ----------------
__global__ void __launch_bounds__(256) convW(const float* __restrict__ s0, const float* __restrict__ s1,
                                             const float* __restrict__ s2, const float* __restrict__ s3,
                                             const float* __restrict__ s4,
                                             u16* __restrict__ d0, u16* __restrict__ d1, u16* __restrict__ d2,
                                             u16* __restrict__ d3, u16* __restrict__ d4) {
  size_t i = ((size_t)blockIdx.x * 256 + threadIdx.x) << 2;
  if (i >= 1050688) return; // 4*262144 + 33*64
  const float* s; u16* d; size_t off;
  if (i < 262144)       { s = s0; d = d0; off = i; }
  else if (i < 524288)  { s = s1; d = d1; off = i - 262144; }
  else if (i < 786432)  { s = s2; d = d2; off = i - 524288; }
  else if (i < 1048576) { s = s3; d = d3; off = i - 786432; }
  else                  { s = s4; d = d4; off = i - 1048576; }
  float4 f = *(const float4*)(s + off);
  uint2 o;
  o.x = cvtpk(f.x, f.y);
  o.y = cvtpk(f.z, f.w);
  *(uint2*)(d + off) = o;
}

// ---------------- fused Q/K/V projection GEMM: 768 blocks x 512 threads (8 waves) ----------------
// seg 0: Q -> bf16 head-split [B,H,S,64]; seg 1: K same; seg 2: V -> transposed [B*H,64,S].
// A staged as f32 via async gload16 (source pre-swizzled at 16B granule; LDS linear);
// fragment read = 2x ds_read_b128(f32) + 4x cvt_pk. Wave grid 4(M)x2(N): each wave owns 32x64.
// XCD-chunked block swizzle keeps the 4 bn-blocks of one A row-block on the same XCD's L2.
__global__ void __launch_bounds__(512) qkv_gemm(const float* __restrict__ Aq, const float* __restrict__ Ak,
                                                const float* __restrict__ Av, const u16* __restrict__ Wqb,
                                                const u16* __restrict__ Wkb, const u16* __restrict__ Wvb,
                                                const float* __restrict__ bq, const float* __restrict__ bk,
                                                const float* __restrict__ bv, u16* __restrict__ Qh,
                                                u16* __restrict__ Kh, u16* __restrict__ Vt) {
  __shared__ float Asf[128 * 64];   // 32 KB f32 A tile
  __shared__ u16 Bs[128 * 64];      // 16 KB bf16 W tile
  // 768 blocks, 8 XCDs, 96 per XCD (exact): XCD x gets logical work [96x, 96x+96)
  const int w = (blockIdx.x & 7) * 96 + (blockIdx.x >> 3);
  const int seg = w >> 8, bid = w & 255;
  const float* Af = seg == 0 ? Aq : (seg == 1 ? Ak : Av);
  const u16* W = seg == 0 ? Wqb : (seg == 1 ? Wkb : Wvb);
  const float* bias = seg == 0 ? bq : (seg == 1 ? bk : bv);
  const int tid = threadIdx.x, lane = tid & 63, wid = tid >> 6;   // wid 0..7
  const int c = lane & 15, g = lane >> 4;
  const int bm = bid >> 2, bn = bid & 3;
  const int m0 = bm << 7, n0 = bn << 7;
  const int wrow = (wid & 3) << 5;    // 0/32/64/96
  const int wcol = (wid >> 2) << 6;   // 0/64

  const f32x4 ZF = {0.f, 0.f, 0.f, 0.f};
  f32x4 acc[2][4];
#pragma unroll
  for (int i = 0; i < 2; ++i)
#pragma unroll
    for (int j = 0; j < 4; ++j) acc[i][j] = ZF;

  for (int kt = 0; kt < 512; kt += 64) {
    __syncthreads();
    // A: f32, 2048 x 16B granules over 8 waves (4 gloads/wave)
#pragma unroll
    for (int j = 0; j < 4; ++j) {
      int s0 = ((wid << 2) | j) << 6;       // granule base (wave-uniform)
      int s = s0 + lane;
      int row = s >> 4;                     // 16 granules per 256B row
      int colb_s = ((s & 15) << 4) ^ ((row & 7) << 4);
      gload16((const char*)Af + (((size_t)(m0 + row)) << 11) + (kt << 2) + colb_s,
              (char*)Asf + (s0 << 4));
    }
    // W: bf16, 1024 x 16B granules over 8 waves (2 gloads/wave)
#pragma unroll
    for (int j = 0; j < 2; ++j) {
      int s0 = ((wid << 1) | j) << 6;
      int s = s0 + lane;
      int row = s >> 3;                     // 8 granules per 128B row
      int off = ((s & 7) << 4) ^ ((row & 7) << 4);
      gload16((const char*)W + ((((size_t)(n0 + row)) << 9) + kt) * 2 + off,
              (char*)Bs + (s0 << 4));
    }
    __syncthreads();
#pragma unroll
    for (int kk = 0; kk < 2; ++kk) {
      bf16x8 af[2], bfr[4];
#pragma unroll
      for (int rt = 0; rt < 2; ++rt) {
        int row = wrow + (rt << 4) + c;
        int swz = (row & 7) << 4;
        const char* pA = (const char*)Asf + row * 256;
        int bb = (kk << 7) + (g << 5);      // byte col base (32B aligned)
        float4 f0 = *(const float4*)(pA + (bb ^ swz));
        float4 f1 = *(const float4*)(pA + ((bb + 16) ^ swz));
        uint4 aw;
        aw.x = cvtpk(f0.x, f0.y); aw.y = cvtpk(f0.z, f0.w);
        aw.z = cvtpk(f1.x, f1.y); aw.w = cvtpk(f1.z, f1.w);
        af[rt] = __builtin_bit_cast(bf16x8, aw);
      }
#pragma unroll
      for (int ct = 0; ct < 4; ++ct) {
        int row = wcol + (ct << 4) + c;
        bfr[ct] = *(const bf16x8*)((const char*)Bs + row * 128 + (((kk << 6) | (g << 4)) ^ ((row & 7) << 4)));
      }
#pragma unroll
      for (int rt = 0; rt < 2; ++rt)
#pragma unroll
        for (int ct = 0; ct < 4; ++ct) acc[rt][ct] = MFMA16(af[rt], bfr[ct], acc[rt][ct]);
    }
  }

#pragma unroll
  for (int rt = 0; rt < 2; ++rt)
#pragma unroll
    for (int ct = 0; ct < 4; ++ct) {
      int n = n0 + wcol + (ct << 4) + c;
      float bv2 = bias[n];
      if (seg == 2) {
        int b2 = m0 >> 10;
        int sbase = (m0 & 1023) + wrow + (rt << 4) + (g << 2);
        int h2 = n >> 6, d2 = n & 63;
        uint2 o;
        o.x = cvtpk(acc[rt][ct][0] + bv2, acc[rt][ct][1] + bv2);
        o.y = cvtpk(acc[rt][ct][2] + bv2, acc[rt][ct][3] + bv2);
        *(uint2*)(Vt + ((((size_t)((b2 << 3) + h2) << 6) + d2) << 10) + sbase) = o;
      } else {
        u16* out = seg == 0 ? Qh : Kh;
#pragma unroll
        for (int r = 0; r < 4; ++r) {
          int m = m0 + wrow + (rt << 4) + (g << 2) + r;
          int b = m >> 10, s = m & 1023, h = n >> 6, d = n & 63;
          out[(((((size_t)(b * H_ + h)) << 10) + s) << 6) + d] = f2bf(acc[rt][ct][r] + bv2);
        }
      }
    }
}

// ---------------- output GEMM: 256 blocks x 512 threads (8 waves), C fp32 [M][512] ----------------
__global__ void __launch_bounds__(512) gemm_out(const u16* __restrict__ A, const u16* __restrict__ W,
                                                const float* __restrict__ bias, float* __restrict__ out) {
  __shared__ u16 As[128 * 64];
  __shared__ u16 Bs[128 * 64];
  // XCD swizzle: 256 blocks, 32 per XCD (exact)
  const int wb = (blockIdx.x & 7) * 32 + (blockIdx.x >> 3);
  const int tid = threadIdx.x, lane = tid & 63, wid = tid >> 6;
  const int c = lane & 15, g = lane >> 4;
  const int bm = wb >> 2, bn = wb & 3;
  const int m0 = bm << 7, n0 = bn << 7;
  const int wrow = (wid & 3) << 5;    // 0/32/64/96
  const int wcol = (wid >> 2) << 6;   // 0/64

  const f32x4 ZF = {0.f, 0.f, 0.f, 0.f};
  f32x4 acc[2][4];
#pragma unroll
  for (int i = 0; i < 2; ++i)
#pragma unroll
    for (int j = 0; j < 4; ++j) acc[i][j] = ZF;

  for (int kt = 0; kt < 512; kt += 64) {
    __syncthreads();
#pragma unroll
    for (int j = 0; j < 2; ++j) {
      int s0 = ((wid << 1) | j) << 6;
      int s = s0 + lane;
      int row = s >> 3;
      int off = ((s & 7) << 4) ^ ((row & 7) << 4);
      gload16((const char*)A + ((((size_t)(m0 + row)) << 9) + kt) * 2 + off, (char*)As + (s0 << 4));
      gload16((const char*)W + ((((size_t)(n0 + row)) << 9) + kt) * 2 + off, (char*)Bs + (s0 << 4));
    }
    __syncthreads();
#pragma unroll
    for (int kk = 0; kk < 2; ++kk) {
      bf16x8 af[2], bfr[4];
#pragma unroll
      for (int rt = 0; rt < 2; ++rt) {
        int row = wrow + (rt << 4) + c;
        af[rt] = *(const bf16x8*)((const char*)As + row * 128 + (((kk << 6) | (g << 4)) ^ ((row & 7) << 4)));
      }
#pragma unroll
      for (int ct = 0; ct < 4; ++ct) {
        int row = wcol + (ct << 4) + c;
        bfr[ct] = *(const bf16x8*)((const char*)Bs + row * 128 + (((kk << 6) | (g << 4)) ^ ((row & 7) << 4)));
      }
#pragma unroll
      for (int rt = 0; rt < 2; ++rt)
#pragma unroll
        for (int ct = 0; ct < 4; ++ct) acc[rt][ct] = MFMA16(af[rt], bfr[ct], acc[rt][ct]);
    }
  }

#pragma unroll
  for (int rt = 0; rt < 2; ++rt)
#pragma unroll
    for (int ct = 0; ct < 4; ++ct) {
      int n = n0 + wcol + (ct << 4) + c;
      float bv = bias[n];
#pragma unroll
      for (int r = 0; r < 4; ++r) {
        int m = m0 + wrow + (rt << 4) + (g << 2) + r;
        out[(((size_t)m) << 9) + n] = acc[rt][ct][r] + bv;
      }
    }
}

// ---------------- flash attention: round-4 structure (8 waves, 128 q, fused qrel + rel-V) ----------------
// lane (c,g) of wave wid owns q = qbase + wid*16 + c everywhere.
__global__ void __launch_bounds__(512) flash_kernel(const u16* __restrict__ Qh, const u16* __restrict__ Kh,
                                                    const u16* __restrict__ Vt, const u16* __restrict__ relkb,
                                                    const float* __restrict__ relv, u16* __restrict__ Xout) {
  __shared__ u16 Ks[2][64 * 64];
  __shared__ u16 Vs[2][64 * 64];
  __shared__ u16 Ps[128 * 64];
  __shared__ float qrelS[128 * 34];   // exp2-domain bias table; overlaid by rvT in epilogue
  __shared__ u16 Pband[128 * 32];     // unnormalized bf16 band probs; slot 0 = low bucket
  __shared__ float rv32S[64];

  const int tid = threadIdx.x, lane = tid & 63, wid = tid >> 6;
  const int c = lane & 15, g = lane >> 4;
  // XCD swizzle: 8 chunks of 64 consecutive blocks
  const int swz = ((blockIdx.x & 7) << 6) | (blockIdx.x >> 3);
  const int bh = swz >> 3, qt = swz & 7;
  const int qbase = qt << 7;
  const size_t rowbase = ((size_t)bh) << 10;
  const int qloc = (wid << 4) + c;
  const float K1 = 0.51013619f;   // (1/sqrt(8)) * log2(e)
  const float C0 = 24.0f;

  // Q fragments (issue loads first)
  bf16x8 qa[2];
  {
    const u16* qptr = Qh + ((rowbase + qbase + qloc) << 6);
    qa[0] = *(const bf16x8*)(qptr + (g << 3));
    qa[1] = *(const bf16x8*)(qptr + 32 + (g << 3));
  }

#define STAGE(buf, kt_) do { \
    const int k64_ = (kt_) << 6; \
    int L_ = (wid << 10) + lane * 16; \
    int row_ = L_ >> 7; \
    int off_ = (L_ & 127) ^ ((row_ & 7) << 4); \
    gload16((const char*)Kh + ((rowbase + k64_ + row_) << 7) + off_, (char*)Ks[buf] + (wid << 10)); \
    gload16((const char*)Vt + ((((size_t)bh << 6) + row_) << 11) + (k64_ << 1) + off_, (char*)Vs[buf] + (wid << 10)); \
  } while (0)

  STAGE(0, 0);

  // zero Pband (8192B), load rv32
  ((uint4*)Pband)[tid] = uint4{0, 0, 0, 0};
  if (tid < 64) rv32S[tid] = relv[2048 + tid];

  // qrel in prologue: qrelS[q][r] = (Q[q,:].relk[r,:]) * K1 - C0, via 6 MFMAs per wave
  {
    const f32x4 ZF = {0.f, 0.f, 0.f, 0.f};
#pragma unroll
    for (int t = 0; t < 3; ++t) {
      int rr = t * 16 + c; if (rr > 32) rr = 32;
      f32x4 qr = ZF;
#pragma unroll
      for (int kk = 0; kk < 2; ++kk) {
        bf16x8 ar = *(const bf16x8*)(relkb + (rr << 6) + (kk << 5) + (g << 3));
        qr = MFMA16(ar, qa[kk], qr);
      }
#pragma unroll
      for (int j = 0; j < 4; ++j) {
        int r = t * 16 + (g << 2) + j;
        if (r < 33) qrelS[qloc * 34 + r] = qr[j] * K1 - C0;
      }
    }
  }
  __syncthreads();   // covers STAGE(0), Pband init, qrelS, rv32S

  const float bias_lo = qrelS[qloc * 34 + 0];
  const float bias_hi = qrelS[qloc * 34 + 32];

  // hoisted loop-invariant LDS byte offsets
  int koff[4][2], voff[4][2], poffw[4];
#pragma unroll
  for (int t = 0; t < 4; ++t) {
#pragma unroll
    for (int kk = 0; kk < 2; ++kk)
      koff[t][kk] = ((t << 4) + c) * 128 + ((((kk << 6) | (g << 4))) ^ ((c & 7) << 4));
#pragma unroll
    for (int h2 = 0; h2 < 2; ++h2)
      voff[t][h2] = ((t << 4) + c) * 128 + ((((h2 << 6) | (g << 4))) ^ ((c & 7) << 4));
    poffw[t] = qloc * 128 + (((t << 5) | (g << 3)) ^ ((c & 7) << 4));
  }
  const int pr0 = qloc * 128 + ((g << 4) ^ ((c & 7) << 4));
  const int pr1 = pr0 ^ 64;

  const f32x4 ZF = {0.f, 0.f, 0.f, 0.f};
  f32x4 acc[4] = {ZF, ZF, ZF, ZF};
  float lsum = 0.f, lowsum = 0.f, psum = 0.f;

  for (int kt = 0; kt < 16; ++kt) {
    const int cur = kt & 1;
    if (kt < 15) STAGE(cur ^ 1, kt + 1);   // prefetch into other buffer

    // QK^T swapped: sa[t][j] = S[k = kt*64 + t*16 + g*4 + j][q = own]
    f32x4 sa[4];
#pragma unroll
    for (int t = 0; t < 4; ++t) {
      sa[t] = ZF;
#pragma unroll
      for (int kk = 0; kk < 2; ++kk) {
        bf16x8 bk = *(const bf16x8*)((const char*)Ks + (cur << 13) + koff[t][kk]);
        sa[t] = MFMA16(bk, qa[kk], sa[t]);
      }
    }

    const int D0 = (kt << 6) - qbase;
    float p[4][4];
    if (D0 >= 192) {            // all dlt >= 17: high bucket
      float s = 0.f;
#pragma unroll
      for (int t = 0; t < 4; ++t)
#pragma unroll
        for (int j = 0; j < 4; ++j) {
          float pe = __builtin_amdgcn_exp2f(fmaf(sa[t][j], K1, bias_hi));
          p[t][j] = pe; s += pe;
        }
      lsum += s;
    } else if (D0 <= -128) {    // all dlt <= -17: low bucket
      float s = 0.f;
#pragma unroll
      for (int t = 0; t < 4; ++t)
#pragma unroll
        for (int j = 0; j < 4; ++j) {
          float pe = __builtin_amdgcn_exp2f(fmaf(sa[t][j], K1, bias_lo));
          p[t][j] = pe; s += pe;
        }
      lsum += s; lowsum += s;
    } else {                    // boundary tiles (4 of 16)
#pragma unroll
      for (int t = 0; t < 4; ++t)
#pragma unroll
        for (int j = 0; j < 4; ++j) {
          int dlt = D0 + (t << 4) + (g << 2) + j - qloc;
          int idx = dlt < -16 ? 0 : (dlt > 16 ? 32 : dlt + 16);
          float pe = __builtin_amdgcn_exp2f(fmaf(sa[t][j], K1, qrelS[qloc * 34 + idx]));
          p[t][j] = pe;
          lsum += pe;
          if (dlt <= -16) lowsum += pe;
          else if (dlt < 16) { psum += pe; Pband[(qloc << 5) + dlt + 16] = f2bf(pe); }
        }
    }

    // P -> LDS (own row), then PV swapped: acc[dt][j] = O[d = dt*16+g*4+j][q = own]
#pragma unroll
    for (int t = 0; t < 4; ++t) {
      uint2 pk;
      pk.x = cvtpk(p[t][0], p[t][1]);
      pk.y = cvtpk(p[t][2], p[t][3]);
      *(uint2*)((char*)Ps + poffw[t]) = pk;
    }
    bf16x8 pb0 = *(const bf16x8*)((const char*)Ps + pr0);
    bf16x8 pb1 = *(const bf16x8*)((const char*)Ps + pr1);
#pragma unroll
    for (int dt = 0; dt < 4; ++dt) {
      bf16x8 av0 = *(const bf16x8*)((const char*)Vs + (cur << 13) + voff[dt][0]);
      bf16x8 av1 = *(const bf16x8*)((const char*)Vs + (cur << 13) + voff[dt][1]);
      acc[dt] = MFMA16(av0, pb0, acc[dt]);
      acc[dt] = MFMA16(av1, pb1, acc[dt]);
    }
    __syncthreads();   // drains prefetch + protects dbuf swap
  }

  // ---- epilogue ----
  lsum += __shfl_xor(lsum, 16);   lsum += __shfl_xor(lsum, 32);
  lowsum += __shfl_xor(lowsum, 16); lowsum += __shfl_xor(lowsum, 32);
  psum += __shfl_xor(psum, 16);   psum += __shfl_xor(psum, 32);
  const float inv = 1.f / lsum;
  const float hsum = lsum - lowsum - psum;   // unnormalized high-bucket mass

  if (g == 0) Pband[qloc << 5] = f2bf(lowsum);   // low bucket slot (unnormalized)

  // overlay rv^T (bf16 [d][r=0..31]) into dead qrelS
  u16* rvT = (u16*)qrelS;
  for (int i = tid; i < 4096; i += 512) rvT[i] = f2bf(relv[((i & 31) << 6) + (i >> 5)]);
  __syncthreads();

  // acc += rv^T[d][r] * Pband[r][q]  (band + low), all unnormalized
  bf16x8 pb2 = *(const bf16x8*)((const u16*)Pband + (qloc << 5) + (g << 3));
#pragma unroll
  for (int dt = 0; dt < 4; ++dt) {
    bf16x8 av = *(const bf16x8*)(rvT + (((dt << 4) + c) << 5) + (g << 3));
    acc[dt] = MFMA16(av, pb2, acc[dt]);
  }

  const int b = bh >> 3, h = bh & 7;
  const int q = qbase + qloc;
  u16* xb = Xout + ((((size_t)b << 10) + q) << 9) + (h << 6);
#pragma unroll
  for (int dt = 0; dt < 4; ++dt) {
    int d0 = (dt << 4) + (g << 2);
    float v0 = (acc[dt][0] + hsum * rv32S[d0 + 0]) * inv;
    float v1 = (acc[dt][1] + hsum * rv32S[d0 + 1]) * inv;
    float v2 = (acc[dt][2] + hsum * rv32S[d0 + 2]) * inv;
    float v3 = (acc[dt][3] + hsum * rv32S[d0 + 3]) * inv;
    uint2 o;
    o.x = cvtpk(v0, v1);
    o.y = cvtpk(v2, v3);
    *(uint2*)(xb + d0) = o;
  }
#undef STAGE
}

// ---------------- launch ----------------
extern "C" void kernel_launch(void* const* d_in, const int* in_sizes, int n_in,
                              void* d_out, int out_size, void* d_ws, size_t ws_size,
                              hipStream_t stream) {
  (void)in_sizes; (void)n_in; (void)out_size; (void)ws_size;
  const float* query = (const float*)d_in[0];
  const float* key   = (const float*)d_in[1];
  const float* value = (const float*)d_in[2];
  const float* Wq = (const float*)d_in[3];
  const float* bq = (const float*)d_in[4];
  const float* Wk = (const float*)d_in[5];
  const float* bk = (const float*)d_in[6];
  const float* Wv = (const float*)d_in[7];
  const float* bv = (const float*)d_in[8];
  const float* Wo = (const float*)d_in[9];
  const float* bo = (const float*)d_in[10];
  const float* relk = (const float*)d_in[11];
  const float* relv = (const float*)d_in[12];

  char* ws = (char*)d_ws;
  u16*   Wqb   = (u16*)(ws + 25165824);
  u16*   Wkb   = (u16*)(ws + 25690112);
  u16*   Wvb   = (u16*)(ws + 26214400);
  u16*   Wob   = (u16*)(ws + 26738688);
  u16*   relkb = (u16*)(ws + 27262976);   // 33*64 bf16
  u16*   Qh    = (u16*)(ws + 27271168);
  u16*   Kh    = (u16*)(ws + 35659776);
  u16*   Vt    = (u16*)(ws + 52436992);
  u16*   Xout  = (u16*)(ws + 70262784);

  convW<<<1027, 256, 0, stream>>>(Wq, Wk, Wv, Wo, relk, Wqb, Wkb, Wvb, Wob, relkb);
  qkv_gemm<<<768, 512, 0, stream>>>(query, key, value, Wqb, Wkb, Wvb, bq, bk, bv, Qh, Kh, Vt);
  flash_kernel<<<512, 512, 0, stream>>>(Qh, Kh, Vt, relkb, relv, Xout);
  gemm_out<<<256, 512, 0, stream>>>(Xout, Wob, bo, (float*)d_out);
}

// Round 15
// 86.021 us; speedup vs baseline: 1.4861x; 1.0037x over previous
//
#include <hip/hip_runtime.h>

typedef unsigned short u16;
typedef float f32x4 __attribute__((ext_vector_type(4)));
typedef __bf16 bf16x8 __attribute__((ext_vector_type(8)));

#define MFMA16(a, b, c) __builtin_amdgcn_mfma_f32_16x16x32_bf16((a), (b), (c), 0, 0, 0)

#define B_ 8
#define H_ 8
#define S_ 1024

__device__ __forceinline__ u16 f2bf(float f) {
  unsigned u = __float_as_uint(f);
  return (u16)((u + 0x7fffu + ((u >> 16) & 1u)) >> 16);
}
// pack 2 f32 -> 2 bf16 in one instr (dst.lo = a, dst.hi = b)
__device__ __forceinline__ unsigned cvtpk(float a, float b) {
  unsigned r;
  asm("v_cvt_pk_bf16_f32 %0, %1, %2" : "=v"(r) : "v"(a), "v"(b));
  return r;
}
// async global->LDS, 16B per lane. LDS dest = wave-uniform base + lane*16.
__device__ __forceinline__ void gload16(const void* g, void* l) {
  __builtin_amdgcn_global_load_lds((__attribute__((address_space(1))) const void*)g,
                                   (__attribute__((address_space(3))) void*)l, 16, 0, 0);
}

// ---------------- weights + relk fp32->bf16 (3.15 MB only) ----------------
__global__ void __launch_bounds__(256) convW(const float* __restrict__ s0, const float* __restrict__ s1,
                                             const float* __restrict__ s2, const float* __restrict__ s3,
                                             const float* __restrict__ s4,
                                             u16* __restrict__ d0, u16* __restrict__ d1, u16* __restrict__ d2,
                                             u16* __restrict__ d3, u16* __restrict__ d4) {
  size_t i = ((size_t)blockIdx.x * 256 + threadIdx.x) << 2;
  if (i >= 1050688) return; // 4*262144 + 33*64
  const float* s; u16* d; size_t off;
  if (i < 262144)       { s = s0; d = d0; off = i; }
  else if (i < 524288)  { s = s1; d = d1; off = i - 262144; }
  else if (i < 786432)  { s = s2; d = d2; off = i - 524288; }
  else if (i < 1048576) { s = s3; d = d3; off = i - 786432; }
  else                  { s = s4; d = d4; off = i - 1048576; }
  float4 f = *(const float4*)(s + off);
  uint2 o;
  o.x = cvtpk(f.x, f.y);
  o.y = cvtpk(f.z, f.w);
  *(uint2*)(d + off) = o;
}

// ---------------- fused Q/K/V projection GEMM: 768 blocks x 512 threads, BK=32, double-buffered ----------------
// seg 0: Q -> bf16 head-split [B,H,S,64]; seg 1: K same; seg 2: V -> transposed [B*H,64,S].
// Flash-proven schedule: STAGE(next tile) BEFORE compute(cur), ONE barrier per iteration --
// the prefetch has the whole compute phase (x 24 waves/CU) to cover HBM/L2 latency; the
// barrier's vmcnt drain then waits on loads that already landed.
// A staged as f32 (16B-granule XOR source swizzle, LDS linear); fragment read = 2x ds_read_b128 + 4x cvt_pk.
// XCD-chunked block swizzle keeps the 4 bn-blocks of one A row-block on the same XCD's L2.
__global__ void __launch_bounds__(512) qkv_gemm(const float* __restrict__ Aq, const float* __restrict__ Ak,
                                                const float* __restrict__ Av, const u16* __restrict__ Wqb,
                                                const u16* __restrict__ Wkb, const u16* __restrict__ Wvb,
                                                const float* __restrict__ bq, const float* __restrict__ bk,
                                                const float* __restrict__ bv, u16* __restrict__ Qh,
                                                u16* __restrict__ Kh, u16* __restrict__ Vt) {
  __shared__ float Asf[2][128 * 32];   // 2 x 16 KB f32 A tiles
  __shared__ u16 Bs[2][128 * 32];      // 2 x 8 KB bf16 W tiles
  // 768 blocks, 8 XCDs, 96 per XCD (exact): XCD x gets logical work [96x, 96x+96)
  const int w = (blockIdx.x & 7) * 96 + (blockIdx.x >> 3);
  const int seg = w >> 8, bid = w & 255;
  const float* Af = seg == 0 ? Aq : (seg == 1 ? Ak : Av);
  const u16* W = seg == 0 ? Wqb : (seg == 1 ? Wkb : Wvb);
  const float* bias = seg == 0 ? bq : (seg == 1 ? bk : bv);
  const int tid = threadIdx.x, lane = tid & 63, wid = tid >> 6;   // wid 0..7
  const int c = lane & 15, g = lane >> 4;
  const int bm = bid >> 2, bn = bid & 3;
  const int m0 = bm << 7, n0 = bn << 7;
  const int wrow = (wid & 3) << 5;    // 0/32/64/96
  const int wcol = (wid >> 2) << 6;   // 0/64

  // stage k-tile starting at element kt_ into buffer buf: A 1024 granules (2/thread), W 512 (1/thread)
#define STAGEQ(buf, kt_) do { \
    _Pragma("unroll") \
    for (int j_ = 0; j_ < 2; ++j_) { \
      int s0_ = ((wid << 1) | j_) << 6; \
      int s_ = s0_ + lane; \
      int row_ = s_ >> 3; \
      int sl_ = (s_ & 7) ^ (row_ & 7); \
      gload16((const char*)Af + ((((size_t)(m0 + row_)) << 9) + (kt_)) * 4 + (sl_ << 4), \
              (char*)Asf[buf] + (s0_ << 4)); \
    } \
    { \
      int s0_ = wid << 6; \
      int s_ = s0_ + lane; \
      int row_ = s_ >> 2; \
      int sl_ = (s_ & 3) ^ (row_ & 3); \
      gload16((const char*)W + ((((size_t)(n0 + row_)) << 9) + (kt_)) * 2 + (sl_ << 4), \
              (char*)Bs[buf] + (s0_ << 4)); \
    } \
  } while (0)

  const f32x4 ZF = {0.f, 0.f, 0.f, 0.f};
  f32x4 acc[2][4];
#pragma unroll
  for (int i = 0; i < 2; ++i)
#pragma unroll
    for (int j = 0; j < 4; ++j) acc[i][j] = ZF;

  STAGEQ(0, 0);
  __syncthreads();   // drain prologue stage

  for (int it = 0; it < 16; ++it) {
    const int cur = it & 1;
    if (it < 15) STAGEQ(cur ^ 1, (it + 1) << 5);   // prefetch next tile, hides under compute

    bf16x8 af[2], bfr[4];
#pragma unroll
    for (int rt = 0; rt < 2; ++rt) {
      int row = wrow + (rt << 4) + c;
      const char* pA = (const char*)Asf[cur] + row * 128;
      int sw = row & 7;
      float4 f0 = *(const float4*)(pA + ((((g << 1) | 0) ^ sw) << 4));
      float4 f1 = *(const float4*)(pA + ((((g << 1) | 1) ^ sw) << 4));
      uint4 aw;
      aw.x = cvtpk(f0.x, f0.y); aw.y = cvtpk(f0.z, f0.w);
      aw.z = cvtpk(f1.x, f1.y); aw.w = cvtpk(f1.z, f1.w);
      af[rt] = __builtin_bit_cast(bf16x8, aw);
    }
#pragma unroll
    for (int ct = 0; ct < 4; ++ct) {
      int row = wcol + (ct << 4) + c;
      bfr[ct] = *(const bf16x8*)((const char*)Bs[cur] + row * 64 + ((g ^ (row & 3)) << 4));
    }
#pragma unroll
    for (int rt = 0; rt < 2; ++rt)
#pragma unroll
      for (int ct = 0; ct < 4; ++ct) acc[rt][ct] = MFMA16(af[rt], bfr[ct], acc[rt][ct]);

    if (it < 15) __syncthreads();   // drains prefetch + gates buffer swap
  }

#pragma unroll
  for (int rt = 0; rt < 2; ++rt)
#pragma unroll
    for (int ct = 0; ct < 4; ++ct) {
      int n = n0 + wcol + (ct << 4) + c;
      float bv2 = bias[n];
      if (seg == 2) {
        int b2 = m0 >> 10;
        int sbase = (m0 & 1023) + wrow + (rt << 4) + (g << 2);
        int h2 = n >> 6, d2 = n & 63;
        uint2 o;
        o.x = cvtpk(acc[rt][ct][0] + bv2, acc[rt][ct][1] + bv2);
        o.y = cvtpk(acc[rt][ct][2] + bv2, acc[rt][ct][3] + bv2);
        *(uint2*)(Vt + ((((size_t)((b2 << 3) + h2) << 6) + d2) << 10) + sbase) = o;
      } else {
        u16* out = seg == 0 ? Qh : Kh;
#pragma unroll
        for (int r = 0; r < 4; ++r) {
          int m = m0 + wrow + (rt << 4) + (g << 2) + r;
          int b = m >> 10, s = m & 1023, h = n >> 6, d = n & 63;
          out[(((((size_t)(b * H_ + h)) << 10) + s) << 6) + d] = f2bf(acc[rt][ct][r] + bv2);
        }
      }
    }
#undef STAGEQ
}

// ---------------- output GEMM: 256 blocks x 512 threads, BK=32, double-buffered ----------------
__global__ void __launch_bounds__(512) gemm_out(const u16* __restrict__ A, const u16* __restrict__ W,
                                                const float* __restrict__ bias, float* __restrict__ out) {
  __shared__ u16 As2[2][128 * 32];   // 2 x 8 KB
  __shared__ u16 Bs2[2][128 * 32];   // 2 x 8 KB
  // XCD swizzle: 256 blocks, 32 per XCD (exact)
  const int wb = (blockIdx.x & 7) * 32 + (blockIdx.x >> 3);
  const int tid = threadIdx.x, lane = tid & 63, wid = tid >> 6;
  const int c = lane & 15, g = lane >> 4;
  const int bm = wb >> 2, bn = wb & 3;
  const int m0 = bm << 7, n0 = bn << 7;
  const int wrow = (wid & 3) << 5;    // 0/32/64/96
  const int wcol = (wid >> 2) << 6;   // 0/64

#define STAGEO(buf, kt_) do { \
    int s0_ = wid << 6; \
    int s_ = s0_ + lane; \
    int row_ = s_ >> 2; \
    int sl_ = (s_ & 3) ^ (row_ & 3); \
    gload16((const char*)A + ((((size_t)(m0 + row_)) << 9) + (kt_)) * 2 + (sl_ << 4), \
            (char*)As2[buf] + (s0_ << 4)); \
    gload16((const char*)W + ((((size_t)(n0 + row_)) << 9) + (kt_)) * 2 + (sl_ << 4), \
            (char*)Bs2[buf] + (s0_ << 4)); \
  } while (0)

  const f32x4 ZF = {0.f, 0.f, 0.f, 0.f};
  f32x4 acc[2][4];
#pragma unroll
  for (int i = 0; i < 2; ++i)
#pragma unroll
    for (int j = 0; j < 4; ++j) acc[i][j] = ZF;

  STAGEO(0, 0);
  __syncthreads();

  for (int it = 0; it < 16; ++it) {
    const int cur = it & 1;
    if (it < 15) STAGEO(cur ^ 1, (it + 1) << 5);

    bf16x8 af[2], bfr[4];
#pragma unroll
    for (int rt = 0; rt < 2; ++rt) {
      int row = wrow + (rt << 4) + c;
      af[rt] = *(const bf16x8*)((const char*)As2[cur] + row * 64 + ((g ^ (row & 3)) << 4));
    }
#pragma unroll
    for (int ct = 0; ct < 4; ++ct) {
      int row = wcol + (ct << 4) + c;
      bfr[ct] = *(const bf16x8*)((const char*)Bs2[cur] + row * 64 + ((g ^ (row & 3)) << 4));
    }
#pragma unroll
    for (int rt = 0; rt < 2; ++rt)
#pragma unroll
      for (int ct = 0; ct < 4; ++ct) acc[rt][ct] = MFMA16(af[rt], bfr[ct], acc[rt][ct]);

    if (it < 15) __syncthreads();
  }

#pragma unroll
  for (int rt = 0; rt < 2; ++rt)
#pragma unroll
    for (int ct = 0; ct < 4; ++ct) {
      int n = n0 + wcol + (ct << 4) + c;
      float bv = bias[n];
#pragma unroll
      for (int r = 0; r < 4; ++r) {
        int m = m0 + wrow + (rt << 4) + (g << 2) + r;
        out[(((size_t)m) << 9) + n] = acc[rt][ct][r] + bv;
      }
    }
#undef STAGEO
}

// ---------------- flash attention: round-4 structure (8 waves, 128 q, fused qrel + rel-V) ----------------
// lane (c,g) of wave wid owns q = qbase + wid*16 + c everywhere.
__global__ void __launch_bounds__(512) flash_kernel(const u16* __restrict__ Qh, const u16* __restrict__ Kh,
                                                    const u16* __restrict__ Vt, const u16* __restrict__ relkb,
                                                    const float* __restrict__ relv, u16* __restrict__ Xout) {
  __shared__ u16 Ks[2][64 * 64];
  __shared__ u16 Vs[2][64 * 64];
  __shared__ u16 Ps[128 * 64];
  __shared__ float qrelS[128 * 34];   // exp2-domain bias table; overlaid by rvT in epilogue
  __shared__ u16 Pband[128 * 32];     // unnormalized bf16 band probs; slot 0 = low bucket
  __shared__ float rv32S[64];

  const int tid = threadIdx.x, lane = tid & 63, wid = tid >> 6;
  const int c = lane & 15, g = lane >> 4;
  // XCD swizzle: 8 chunks of 64 consecutive blocks
  const int swz = ((blockIdx.x & 7) << 6) | (blockIdx.x >> 3);
  const int bh = swz >> 3, qt = swz & 7;
  const int qbase = qt << 7;
  const size_t rowbase = ((size_t)bh) << 10;
  const int qloc = (wid << 4) + c;
  const float K1 = 0.51013619f;   // (1/sqrt(8)) * log2(e)
  const float C0 = 24.0f;

  // Q fragments (issue loads first)
  bf16x8 qa[2];
  {
    const u16* qptr = Qh + ((rowbase + qbase + qloc) << 6);
    qa[0] = *(const bf16x8*)(qptr + (g << 3));
    qa[1] = *(const bf16x8*)(qptr + 32 + (g << 3));
  }

#define STAGE(buf, kt_) do { \
    const int k64_ = (kt_) << 6; \
    int L_ = (wid << 10) + lane * 16; \
    int row_ = L_ >> 7; \
    int off_ = (L_ & 127) ^ ((row_ & 7) << 4); \
    gload16((const char*)Kh + ((rowbase + k64_ + row_) << 7) + off_, (char*)Ks[buf] + (wid << 10)); \
    gload16((const char*)Vt + ((((size_t)bh << 6) + row_) << 11) + (k64_ << 1) + off_, (char*)Vs[buf] + (wid << 10)); \
  } while (0)

  STAGE(0, 0);

  // zero Pband (8192B), load rv32
  ((uint4*)Pband)[tid] = uint4{0, 0, 0, 0};
  if (tid < 64) rv32S[tid] = relv[2048 + tid];

  // qrel in prologue: qrelS[q][r] = (Q[q,:].relk[r,:]) * K1 - C0, via 6 MFMAs per wave
  {
    const f32x4 ZF = {0.f, 0.f, 0.f, 0.f};
#pragma unroll
    for (int t = 0; t < 3; ++t) {
      int rr = t * 16 + c; if (rr > 32) rr = 32;
      f32x4 qr = ZF;
#pragma unroll
      for (int kk = 0; kk < 2; ++kk) {
        bf16x8 ar = *(const bf16x8*)(relkb + (rr << 6) + (kk << 5) + (g << 3));
        qr = MFMA16(ar, qa[kk], qr);
      }
#pragma unroll
      for (int j = 0; j < 4; ++j) {
        int r = t * 16 + (g << 2) + j;
        if (r < 33) qrelS[qloc * 34 + r] = qr[j] * K1 - C0;
      }
    }
  }
  __syncthreads();   // covers STAGE(0), Pband init, qrelS, rv32S

  const float bias_lo = qrelS[qloc * 34 + 0];
  const float bias_hi = qrelS[qloc * 34 + 32];

  // hoisted loop-invariant LDS byte offsets
  int koff[4][2], voff[4][2], poffw[4];
#pragma unroll
  for (int t = 0; t < 4; ++t) {
#pragma unroll
    for (int kk = 0; kk < 2; ++kk)
      koff[t][kk] = ((t << 4) + c) * 128 + ((((kk << 6) | (g << 4))) ^ ((c & 7) << 4));
#pragma unroll
    for (int h2 = 0; h2 < 2; ++h2)
      voff[t][h2] = ((t << 4) + c) * 128 + ((((h2 << 6) | (g << 4))) ^ ((c & 7) << 4));
    poffw[t] = qloc * 128 + (((t << 5) | (g << 3)) ^ ((c & 7) << 4));
  }
  const int pr0 = qloc * 128 + ((g << 4) ^ ((c & 7) << 4));
  const int pr1 = pr0 ^ 64;

  const f32x4 ZF = {0.f, 0.f, 0.f, 0.f};
  f32x4 acc[4] = {ZF, ZF, ZF, ZF};
  float lsum = 0.f, lowsum = 0.f, psum = 0.f;

  for (int kt = 0; kt < 16; ++kt) {
    const int cur = kt & 1;
    if (kt < 15) STAGE(cur ^ 1, kt + 1);   // prefetch into other buffer

    // QK^T swapped: sa[t][j] = S[k = kt*64 + t*16 + g*4 + j][q = own]
    f32x4 sa[4];
#pragma unroll
    for (int t = 0; t < 4; ++t) {
      sa[t] = ZF;
#pragma unroll
      for (int kk = 0; kk < 2; ++kk) {
        bf16x8 bk = *(const bf16x8*)((const char*)Ks + (cur << 13) + koff[t][kk]);
        sa[t] = MFMA16(bk, qa[kk], sa[t]);
      }
    }

    const int D0 = (kt << 6) - qbase;
    float p[4][4];
    if (D0 >= 192) {            // all dlt >= 17: high bucket
      float s = 0.f;
#pragma unroll
      for (int t = 0; t < 4; ++t)
#pragma unroll
        for (int j = 0; j < 4; ++j) {
          float pe = __builtin_amdgcn_exp2f(fmaf(sa[t][j], K1, bias_hi));
          p[t][j] = pe; s += pe;
        }
      lsum += s;
    } else if (D0 <= -128) {    // all dlt <= -17: low bucket
      float s = 0.f;
#pragma unroll
      for (int t = 0; t < 4; ++t)
#pragma unroll
        for (int j = 0; j < 4; ++j) {
          float pe = __builtin_amdgcn_exp2f(fmaf(sa[t][j], K1, bias_lo));
          p[t][j] = pe; s += pe;
        }
      lsum += s; lowsum += s;
    } else {                    // boundary tiles (4 of 16)
#pragma unroll
      for (int t = 0; t < 4; ++t)
#pragma unroll
        for (int j = 0; j < 4; ++j) {
          int dlt = D0 + (t << 4) + (g << 2) + j - qloc;
          int idx = dlt < -16 ? 0 : (dlt > 16 ? 32 : dlt + 16);
          float pe = __builtin_amdgcn_exp2f(fmaf(sa[t][j], K1, qrelS[qloc * 34 + idx]));
          p[t][j] = pe;
          lsum += pe;
          if (dlt <= -16) lowsum += pe;
          else if (dlt < 16) { psum += pe; Pband[(qloc << 5) + dlt + 16] = f2bf(pe); }
        }
    }

    // P -> LDS (own row), then PV swapped: acc[dt][j] = O[d = dt*16+g*4+j][q = own]
#pragma unroll
    for (int t = 0; t < 4; ++t) {
      uint2 pk;
      pk.x = cvtpk(p[t][0], p[t][1]);
      pk.y = cvtpk(p[t][2], p[t][3]);
      *(uint2*)((char*)Ps + poffw[t]) = pk;
    }
    bf16x8 pb0 = *(const bf16x8*)((const char*)Ps + pr0);
    bf16x8 pb1 = *(const bf16x8*)((const char*)Ps + pr1);
#pragma unroll
    for (int dt = 0; dt < 4; ++dt) {
      bf16x8 av0 = *(const bf16x8*)((const char*)Vs + (cur << 13) + voff[dt][0]);
      bf16x8 av1 = *(const bf16x8*)((const char*)Vs + (cur << 13) + voff[dt][1]);
      acc[dt] = MFMA16(av0, pb0, acc[dt]);
      acc[dt] = MFMA16(av1, pb1, acc[dt]);
    }
    __syncthreads();   // drains prefetch + protects dbuf swap
  }

  // ---- epilogue ----
  lsum += __shfl_xor(lsum, 16);   lsum += __shfl_xor(lsum, 32);
  lowsum += __shfl_xor(lowsum, 16); lowsum += __shfl_xor(lowsum, 32);
  psum += __shfl_xor(psum, 16);   psum += __shfl_xor(psum, 32);
  const float inv = 1.f / lsum;
  const float hsum = lsum - lowsum - psum;   // unnormalized high-bucket mass

  if (g == 0) Pband[qloc << 5] = f2bf(lowsum);   // low bucket slot (unnormalized)

  // overlay rv^T (bf16 [d][r=0..31]) into dead qrelS
  u16* rvT = (u16*)qrelS;
  for (int i = tid; i < 4096; i += 512) rvT[i] = f2bf(relv[((i & 31) << 6) + (i >> 5)]);
  __syncthreads();

  // acc += rv^T[d][r] * Pband[r][q]  (band + low), all unnormalized
  bf16x8 pb2 = *(const bf16x8*)((const u16*)Pband + (qloc << 5) + (g << 3));
#pragma unroll
  for (int dt = 0; dt < 4; ++dt) {
    bf16x8 av = *(const bf16x8*)(rvT + (((dt << 4) + c) << 5) + (g << 3));
    acc[dt] = MFMA16(av, pb2, acc[dt]);
  }

  const int b = bh >> 3, h = bh & 7;
  const int q = qbase + qloc;
  u16* xb = Xout + ((((size_t)b << 10) + q) << 9) + (h << 6);
#pragma unroll
  for (int dt = 0; dt < 4; ++dt) {
    int d0 = (dt << 4) + (g << 2);
    float v0 = (acc[dt][0] + hsum * rv32S[d0 + 0]) * inv;
    float v1 = (acc[dt][1] + hsum * rv32S[d0 + 1]) * inv;
    float v2 = (acc[dt][2] + hsum * rv32S[d0 + 2]) * inv;
    float v3 = (acc[dt][3] + hsum * rv32S[d0 + 3]) * inv;
    uint2 o;
    o.x = cvtpk(v0, v1);
    o.y = cvtpk(v2, v3);
    *(uint2*)(xb + d0) = o;
  }
#undef STAGE
}

// ---------------- launch ----------------
extern "C" void kernel_launch(void* const* d_in, const int* in_sizes, int n_in,
                              void* d_out, int out_size, void* d_ws, size_t ws_size,
                              hipStream_t stream) {
  (void)in_sizes; (void)n_in; (void)out_size; (void)ws_size;
  const float* query = (const float*)d_in[0];
  const float* key   = (const float*)d_in[1];
  const float* value = (const float*)d_in[2];
  const float* Wq = (const float*)d_in[3];
  const float* bq = (const float*)d_in[4];
  const float* Wk = (const float*)d_in[5];
  const float* bk = (const float*)d_in[6];
  const float* Wv = (const float*)d_in[7];
  const float* bv = (const float*)d_in[8];
  const float* Wo = (const float*)d_in[9];
  const float* bo = (const float*)d_in[10];
  const float* relk = (const float*)d_in[11];
  const float* relv = (const float*)d_in[12];

  char* ws = (char*)d_ws;
  u16*   Wqb   = (u16*)(ws + 25165824);
  u16*   Wkb   = (u16*)(ws + 25690112);
  u16*   Wvb   = (u16*)(ws + 26214400);
  u16*   Wob   = (u16*)(ws + 26738688);
  u16*   relkb = (u16*)(ws + 27262976);   // 33*64 bf16
  u16*   Qh    = (u16*)(ws + 27271168);
  u16*   Kh    = (u16*)(ws + 35659776);
  u16*   Vt    = (u16*)(ws + 52436992);
  u16*   Xout  = (u16*)(ws + 70262784);

  convW<<<1027, 256, 0, stream>>>(Wq, Wk, Wv, Wo, relk, Wqb, Wkb, Wvb, Wob, relkb);
  qkv_gemm<<<768, 512, 0, stream>>>(query, key, value, Wqb, Wkb, Wvb, bq, bk, bv, Qh, Kh, Vt);
  flash_kernel<<<512, 512, 0, stream>>>(Qh, Kh, Vt, relkb, relv, Xout);
  gemm_out<<<256, 512, 0, stream>>>(Xout, Wob, bo, (float*)d_out);
}